// Round 1
// baseline (769.822 us; speedup 1.0000x reference)
//
#include <hip/hip_runtime.h>

#define NSLOPE 0.2f
#define GEPS 1e-5f

__device__ __forceinline__ float lrelu(float x) { return x >= 0.f ? x : NSLOPE * x; }

// ---------------- Kernel A: fused MLP  h2 = relu(relu(x@W1+b1)@W2+b2) ----------------
__global__ __launch_bounds__(256) void k_mlp(
    const float* __restrict__ x, const float* __restrict__ w1, const float* __restrict__ b1,
    const float* __restrict__ w2, const float* __restrict__ b2, float* __restrict__ h2)
{
    __shared__ float xs[8][256];
    __shared__ float h1s[8][128];
    const int t = threadIdx.x;
    const int n0 = blockIdx.x * 8;
    for (int j = 0; j < 8; ++j) xs[j][t] = x[(size_t)(n0 + j) * 256 + t];
    __syncthreads();
    {
        const int col = t & 127, ng = t >> 7;
        for (int j = 0; j < 4; ++j) {
            const int nd = ng * 4 + j;
            float acc = b1[col];
            #pragma unroll 8
            for (int k = 0; k < 256; ++k) acc = fmaf(xs[nd][k], w1[k * 128 + col], acc);
            h1s[nd][col] = fmaxf(acc, 0.f);
        }
    }
    __syncthreads();
    {
        const int col = t & 63, ng = t >> 6;
        for (int j = 0; j < 2; ++j) {
            const int nd = ng * 2 + j;
            float acc = b2[col];
            #pragma unroll 8
            for (int k = 0; k < 128; ++k) acc = fmaf(h1s[nd][k], w2[k * 64 + col], acc);
            h2[(size_t)(n0 + nd) * 64 + col] = fmaxf(acc, 0.f);
        }
    }
}

// ---------------- Kernel B: GAT1 node features hg1 = h2@g1_w ; a1s/a1d per (node,head) ----------------
__global__ __launch_bounds__(256) void k_gat1_feat(
    const float* __restrict__ h2, const float* __restrict__ w,
    const float* __restrict__ attS, const float* __restrict__ attD,
    float* __restrict__ hg1, float* __restrict__ a1s, float* __restrict__ a1d)
{
    __shared__ float hs[8][64];
    const int t = threadIdx.x;
    const int n0 = blockIdx.x * 8;
    for (int j = 0; j < 2; ++j) {
        const int idx = j * 256 + t;                 // 0..511
        hs[idx >> 6][idx & 63] = h2[(size_t)n0 * 64 + idx];
    }
    __syncthreads();
    const float as = attS[t], ad = attD[t];          // flat [4*64], index = head*64+c == t
    const int head = t >> 6, lane = t & 63;
    for (int nd = 0; nd < 8; ++nd) {
        float acc = 0.f;
        #pragma unroll 8
        for (int k = 0; k < 64; ++k) acc = fmaf(hs[nd][k], w[k * 256 + t], acc);
        hg1[(size_t)(n0 + nd) * 256 + t] = acc;
        float vs = acc * as, vd = acc * ad;
        for (int off = 32; off; off >>= 1) { vs += __shfl_down(vs, off); vd += __shfl_down(vd, off); }
        if (lane == 0) { a1s[(n0 + nd) * 4 + head] = vs; a1d[(n0 + nd) * 4 + head] = vd; }
    }
}

// ---------------- CSR build ----------------
__global__ void k_hist(const int* __restrict__ dst, int* __restrict__ deg, int e) {
    int i = blockIdx.x * 256 + threadIdx.x;
    if (i < e) atomicAdd(&deg[dst[i]], 1);
}

__global__ __launch_bounds__(256) void k_scan1(const int* __restrict__ deg, int* __restrict__ offs,
                                               int* __restrict__ bsum, int n)
{
    __shared__ int sm[256];
    const int t = threadIdx.x;
    const int i = blockIdx.x * 256 + t;
    const int v = (i < n) ? deg[i] : 0;
    sm[t] = v;
    __syncthreads();
    for (int off = 1; off < 256; off <<= 1) {
        int add = (t >= off) ? sm[t - off] : 0;
        __syncthreads();
        sm[t] += add;
        __syncthreads();
    }
    if (i < n) offs[i] = sm[t] - v;
    if (t == 255) bsum[blockIdx.x] = sm[255];
}

__global__ __launch_bounds__(256) void k_scan2(int* __restrict__ bsum, int nb) {
    __shared__ int sm[256];
    const int t = threadIdx.x;
    const int v = (t < nb) ? bsum[t] : 0;
    sm[t] = v;
    __syncthreads();
    for (int off = 1; off < 256; off <<= 1) {
        int add = (t >= off) ? sm[t - off] : 0;
        __syncthreads();
        sm[t] += add;
        __syncthreads();
    }
    if (t < nb) bsum[t] = sm[t] - v;   // exclusive
}

__global__ void k_scan3(int* __restrict__ offs, int* __restrict__ cursor,
                        const int* __restrict__ bsum, int n, int e) {
    int i = blockIdx.x * 256 + threadIdx.x;
    if (i < n) {
        int o = offs[i] + bsum[i >> 8];
        offs[i] = o;
        cursor[i] = o;
    }
    if (i == 0) offs[n] = e;
}

__global__ void k_scatter(const int* __restrict__ src, const int* __restrict__ dst,
                          int* __restrict__ cursor, int* __restrict__ csr, int e) {
    int i = blockIdx.x * 256 + threadIdx.x;
    if (i < e) {
        int p = atomicAdd(&cursor[dst[i]], 1);
        csr[p] = src[i];
    }
}

// ---------------- Kernel D: GAT1 aggregation (online segment softmax + weighted sum) ----------------
__global__ __launch_bounds__(256) void k_gat1_agg(
    const float* __restrict__ hg1, const float* __restrict__ a1s, const float* __restrict__ a1d,
    const int* __restrict__ offs, const int* __restrict__ csr,
    const float* __restrict__ bias, float* __restrict__ out1)
{
    const int d = blockIdx.x, t = threadIdx.x;
    const int start = offs[d], end = offs[d + 1];
    const float4* __restrict__ a1s4 = (const float4*)a1s;
    const float4 adv = ((const float4*)a1d)[d];
    const float ad[4] = {adv.x, adv.y, adv.z, adv.w};

    float m[4], s[4];
    #pragma unroll
    for (int h = 0; h < 4; ++h) { m[h] = -1e30f; s[h] = 0.f; }
    for (int e = start + t; e < end; e += 256) {
        const int sid = csr[e];
        const float4 av = a1s4[sid];
        const float lv[4] = {av.x + ad[0], av.y + ad[1], av.z + ad[2], av.w + ad[3]};
        #pragma unroll
        for (int h = 0; h < 4; ++h) {
            float l = lrelu(lv[h]);
            float nm = fmaxf(m[h], l);
            s[h] = s[h] * __expf(m[h] - nm) + __expf(l - nm);
            m[h] = nm;
        }
    }
    // wave reduce (lane 0 of each wave gets result)
    for (int off = 32; off; off >>= 1) {
        #pragma unroll
        for (int h = 0; h < 4; ++h) {
            float om = __shfl_down(m[h], off), os = __shfl_down(s[h], off);
            float nm = fmaxf(m[h], om);
            s[h] = s[h] * __expf(m[h] - nm) + os * __expf(om - nm);
            m[h] = nm;
        }
    }
    __shared__ float wm[4][4], wsd[4][4];
    __shared__ float fm[4], finv[4];
    const int wave = t >> 6;
    if ((t & 63) == 0) {
        #pragma unroll
        for (int h = 0; h < 4; ++h) { wm[wave][h] = m[h]; wsd[wave][h] = s[h]; }
    }
    __syncthreads();
    if (t == 0) {
        #pragma unroll
        for (int h = 0; h < 4; ++h) {
            float M = wm[0][h], S = wsd[0][h];
            for (int w = 1; w < 4; ++w) {
                float nm = fmaxf(M, wm[w][h]);
                S = S * __expf(M - nm) + wsd[w][h] * __expf(wm[w][h] - nm);
                M = nm;
            }
            fm[h] = M;
            finv[h] = 1.f / (S + 1e-16f);
        }
    }
    __syncthreads();

    __shared__ int sidL[64];
    __shared__ float alphaL[64][4];
    const int head = t >> 6;
    float acc = 0.f;
    for (int base = start; base < end; base += 64) {
        const int cnt = min(64, end - base);
        if (t < cnt) {
            const int sid = csr[base + t];
            sidL[t] = sid;
            const float4 av = a1s4[sid];
            const float lv[4] = {av.x + ad[0], av.y + ad[1], av.z + ad[2], av.w + ad[3]};
            #pragma unroll
            for (int h = 0; h < 4; ++h)
                alphaL[t][h] = __expf(lrelu(lv[h]) - fm[h]) * finv[h];
        }
        __syncthreads();
        for (int i = 0; i < cnt; ++i)
            acc = fmaf(alphaL[i][head], hg1[(size_t)sidL[i] * 256 + t], acc);
        __syncthreads();
    }
    out1[(size_t)d * 256 + t] = acc + bias[t];
}

// ---------------- GraphNorm ----------------
__global__ __launch_bounds__(256) void k_colstat(const float* __restrict__ out1,
    float* __restrict__ colsum, float* __restrict__ colsq, int n)
{
    const int t = threadIdx.x;
    float s = 0.f, q = 0.f;
    for (int r = blockIdx.x; r < n; r += gridDim.x) {
        float v = out1[(size_t)r * 256 + t];
        s += v;
        q += v * v;
    }
    atomicAdd(&colsum[t], s);
    atomicAdd(&colsq[t], q);
}

__global__ void k_norm_params(const float* __restrict__ colsum, const float* __restrict__ colsq,
    const float* __restrict__ gw, const float* __restrict__ gb, const float* __restrict__ gms,
    float* __restrict__ scale, float* __restrict__ shift, int n)
{
    const int t = threadIdx.x;
    const float invn = 1.f / (float)n;
    const float mean = colsum[t] * invn;
    const float msq = colsq[t] * invn;
    const float ms = gms[t];
    // var = E[(h - mean*ms)^2] = E[h^2] - 2*ms*mean^2 + ms^2*mean^2
    const float var = msq - 2.f * ms * mean * mean + ms * ms * mean * mean;
    const float sc = gw[t] * rsqrtf(var + GEPS);
    scale[t] = sc;
    shift[t] = gb[t] - mean * ms * sc;
}

// ---------------- Kernel F: norm+elu then GAT2 features ----------------
__global__ __launch_bounds__(256) void k_gat2_feat(
    const float* __restrict__ out1, const float* __restrict__ scale, const float* __restrict__ shift,
    const float* __restrict__ w, const float* __restrict__ attS, const float* __restrict__ attD,
    float* __restrict__ hg2, float* __restrict__ a2s, float* __restrict__ a2d)
{
    __shared__ float hs[8][256];
    const int t = threadIdx.x;
    const int n0 = blockIdx.x * 8;
    const float sc = scale[t], sh = shift[t];
    for (int j = 0; j < 8; ++j) {
        float v = out1[(size_t)(n0 + j) * 256 + t] * sc + sh;
        hs[j][t] = v > 0.f ? v : (__expf(v) - 1.f);   // elu
    }
    __syncthreads();
    const int col = t & 31, nd = t >> 5;
    float acc = 0.f;
    #pragma unroll 8
    for (int k = 0; k < 256; ++k) acc = fmaf(hs[nd][k], w[k * 32 + col], acc);
    hg2[(size_t)(n0 + nd) * 32 + col] = acc;
    float vs = acc * attS[col], vd = acc * attD[col];
    for (int off = 16; off; off >>= 1) { vs += __shfl_down(vs, off, 32); vd += __shfl_down(vd, off, 32); }
    if (col == 0) { a2s[n0 + nd] = vs; a2d[n0 + nd] = vd; }
}

// ---------------- Kernel G: GAT2 aggregation + bias + log_softmax ----------------
__global__ __launch_bounds__(64) void k_gat2_agg(
    const float* __restrict__ hg2, const float* __restrict__ a2s, const float* __restrict__ a2d,
    const int* __restrict__ offs, const int* __restrict__ csr,
    const float* __restrict__ bias, float* __restrict__ out)
{
    const int d = blockIdx.x, t = threadIdx.x;
    const int start = offs[d], end = offs[d + 1];
    const float adv = a2d[d];
    float m = -1e30f, s = 0.f;
    for (int e = start + t; e < end; e += 64) {
        const int sid = csr[e];
        float l = lrelu(a2s[sid] + adv);
        float nm = fmaxf(m, l);
        s = s * __expf(m - nm) + __expf(l - nm);
        m = nm;
    }
    for (int off = 32; off; off >>= 1) {
        float om = __shfl_xor(m, off), os = __shfl_xor(s, off);
        float nm = fmaxf(m, om);
        s = s * __expf(m - nm) + os * __expf(om - nm);
        m = nm;
    }
    const float inv = 1.f / (s + 1e-16f);

    __shared__ int sidL[64];
    __shared__ float alphaL[64];
    const int c = t & 31, half = t >> 5;
    float acc = 0.f;
    for (int base = start; base < end; base += 64) {
        const int cnt = min(64, end - base);
        if (t < cnt) {
            const int sid = csr[base + t];
            sidL[t] = sid;
            alphaL[t] = __expf(lrelu(a2s[sid] + adv) - m) * inv;
        }
        __syncthreads();
        for (int i = half; i < cnt; i += 2)
            acc = fmaf(alphaL[i], hg2[(size_t)sidL[i] * 32 + c], acc);
        __syncthreads();
    }
    acc += __shfl_xor(acc, 32);
    const float v = acc + bias[c];
    // log_softmax over the 32 channels (lanes 0..31; 32..63 mirror harmlessly)
    float mx = v;
    for (int off = 16; off; off >>= 1) mx = fmaxf(mx, __shfl_xor(mx, off, 32));
    float se = __expf(v - mx);
    for (int off = 16; off; off >>= 1) se += __shfl_xor(se, off, 32);
    if (t < 32) out[(size_t)d * 32 + t] = v - mx - __logf(se);
}

// ---------------- launcher ----------------
extern "C" void kernel_launch(void* const* d_in, const int* in_sizes, int n_in,
                              void* d_out, int out_size, void* d_ws, size_t ws_size,
                              hipStream_t stream)
{
    const float* x    = (const float*)d_in[0];
    const int*   ei   = (const int*)d_in[1];
    const float* t1w  = (const float*)d_in[2];
    const float* t1b  = (const float*)d_in[3];
    const float* t2w  = (const float*)d_in[4];
    const float* t2b  = (const float*)d_in[5];
    const float* g1w  = (const float*)d_in[6];
    const float* g1as = (const float*)d_in[7];
    const float* g1ad = (const float*)d_in[8];
    const float* g1b  = (const float*)d_in[9];
    const float* gnw  = (const float*)d_in[10];
    const float* gnb  = (const float*)d_in[11];
    const float* gnms = (const float*)d_in[12];
    const float* g2w  = (const float*)d_in[13];
    const float* g2as = (const float*)d_in[14];
    const float* g2ad = (const float*)d_in[15];
    const float* g2b  = (const float*)d_in[16];

    const int N = in_sizes[0] / 256;
    const int E = in_sizes[1] / 2;
    const int* srcA = ei;
    const int* dstA = ei + E;

    char* ws = (char*)d_ws;
    size_t cur = 0;
    auto alloc = [&](size_t bytes) -> char* {
        char* p = ws + cur;
        cur += (bytes + 255) & ~(size_t)255;
        return p;
    };
    float* h2     = (float*)alloc((size_t)N * 64 * 4);
    float* hg1    = (float*)alloc((size_t)N * 256 * 4);
    float* a1s    = (float*)alloc((size_t)N * 4 * 4);
    float* a1d    = (float*)alloc((size_t)N * 4 * 4);
    float* out1   = (float*)alloc((size_t)N * 256 * 4);
    float* hg2    = (float*)alloc((size_t)N * 32 * 4);
    float* a2s    = (float*)alloc((size_t)N * 4);
    float* a2d    = (float*)alloc((size_t)N * 4);
    int*   deg    = (int*)alloc((size_t)(N + 1) * 4);
    int*   offs   = (int*)alloc((size_t)(N + 1) * 4);
    int*   cursor = (int*)alloc((size_t)N * 4);
    int*   bsum   = (int*)alloc(1024);
    int*   csr    = (int*)alloc((size_t)E * 4);
    float* colsum = (float*)alloc(1024);
    float* colsq  = (float*)alloc(1024);   // contiguous with colsum
    float* cscale = (float*)alloc(1024);
    float* cshift = (float*)alloc(1024);

    hipMemsetAsync(deg, 0, (size_t)(N + 1) * 4, stream);
    hipMemsetAsync(colsum, 0, 2048, stream);   // colsum + colsq

    const int EB = (E + 255) / 256;
    const int NB = (N + 255) / 256;

    k_mlp<<<N / 8, 256, 0, stream>>>(x, t1w, t1b, t2w, t2b, h2);
    k_gat1_feat<<<N / 8, 256, 0, stream>>>(h2, g1w, g1as, g1ad, hg1, a1s, a1d);
    k_hist<<<EB, 256, 0, stream>>>(dstA, deg, E);
    k_scan1<<<NB, 256, 0, stream>>>(deg, offs, bsum, N);
    k_scan2<<<1, 256, 0, stream>>>(bsum, NB);
    k_scan3<<<NB, 256, 0, stream>>>(offs, cursor, bsum, N, E);
    k_scatter<<<EB, 256, 0, stream>>>(srcA, dstA, cursor, csr, E);
    k_gat1_agg<<<N, 256, 0, stream>>>(hg1, a1s, a1d, offs, csr, g1b, out1);
    k_colstat<<<256, 256, 0, stream>>>(out1, colsum, colsq, N);
    k_norm_params<<<1, 256, 0, stream>>>(colsum, colsq, gnw, gnb, gnms, cscale, cshift, N);
    k_gat2_feat<<<N / 8, 256, 0, stream>>>(out1, cscale, cshift, g2w, g2as, g2ad, hg2, a2s, a2d);
    k_gat2_agg<<<N, 64, 0, stream>>>(hg2, a2s, a2d, offs, csr, g2b, (float*)d_out);
}

// Round 2
// 524.677 us; speedup vs baseline: 1.4672x; 1.4672x over previous
//
#include <hip/hip_runtime.h>

#define NSLOPE 0.2f
#define GEPS 1e-5f

__device__ __forceinline__ float lrelu(float x) { return x >= 0.f ? x : NSLOPE * x; }

// =================== dense transforms: LDS-staged register-blocked GEMMs ===================

// G1: h1 = relu(x @ w1 + b1)   x:[N,256] w1:[256,128]  tile: 64 nodes x 128 cols, K-chunk 64
__global__ __launch_bounds__(256) void k_lin1(const float* __restrict__ x,
    const float* __restrict__ w1, const float* __restrict__ b1,
    float* __restrict__ h1, int n)
{
    __shared__ float xs[64][68];    // [k][node]
    __shared__ float ws[64][132];   // [k][col]
    const int t = threadIdx.x;
    const int n0g = blockIdx.x * 64;
    const int nb = (t & 15) * 4, c0 = (t >> 4) * 8;
    float acc[4][8];
    #pragma unroll
    for (int a = 0; a < 4; ++a)
        #pragma unroll
        for (int b = 0; b < 8; ++b) acc[a][b] = 0.f;

    for (int kc = 0; kc < 4; ++kc) {
        __syncthreads();
        #pragma unroll
        for (int i = 0; i < 4; ++i) {
            const int idx = i * 256 + t;
            const int node = idx >> 4, kk = (idx & 15) * 4;
            int gn = n0g + node; if (gn >= n) gn = n - 1;
            const float4 v = *(const float4*)&x[(size_t)gn * 256 + kc * 64 + kk];
            xs[kk][node] = v.x; xs[kk + 1][node] = v.y; xs[kk + 2][node] = v.z; xs[kk + 3][node] = v.w;
        }
        #pragma unroll
        for (int i = 0; i < 8; ++i) {
            const int idx = i * 256 + t;
            const int kk = idx >> 5, cc = (idx & 31) * 4;
            *(float4*)&ws[kk][cc] = *(const float4*)&w1[(size_t)(kc * 64 + kk) * 128 + cc];
        }
        __syncthreads();
        #pragma unroll 4
        for (int kk = 0; kk < 64; ++kk) {
            const float4 xv = *(const float4*)&xs[kk][nb];
            const float4 wa = *(const float4*)&ws[kk][c0];
            const float4 wb = *(const float4*)&ws[kk][c0 + 4];
            const float xr[4] = {xv.x, xv.y, xv.z, xv.w};
            const float wr[8] = {wa.x, wa.y, wa.z, wa.w, wb.x, wb.y, wb.z, wb.w};
            #pragma unroll
            for (int a = 0; a < 4; ++a)
                #pragma unroll
                for (int b = 0; b < 8; ++b) acc[a][b] = fmaf(xr[a], wr[b], acc[a][b]);
        }
    }
    float bb[8];
    #pragma unroll
    for (int b = 0; b < 8; ++b) bb[b] = b1[c0 + b];
    #pragma unroll
    for (int a = 0; a < 4; ++a) {
        const int gn = n0g + nb + a;
        if (gn < n) {
            float4 o0, o1;
            o0.x = fmaxf(acc[a][0] + bb[0], 0.f); o0.y = fmaxf(acc[a][1] + bb[1], 0.f);
            o0.z = fmaxf(acc[a][2] + bb[2], 0.f); o0.w = fmaxf(acc[a][3] + bb[3], 0.f);
            o1.x = fmaxf(acc[a][4] + bb[4], 0.f); o1.y = fmaxf(acc[a][5] + bb[5], 0.f);
            o1.z = fmaxf(acc[a][6] + bb[6], 0.f); o1.w = fmaxf(acc[a][7] + bb[7], 0.f);
            *(float4*)&h1[(size_t)gn * 128 + c0] = o0;
            *(float4*)&h1[(size_t)gn * 128 + c0 + 4] = o1;
        }
    }
}

// G2: h2 = relu(h1 @ w2 + b2)  h1:[N,128] w2:[128,64]  tile 64x64, K-chunk 64
__global__ __launch_bounds__(256) void k_lin2(const float* __restrict__ h1,
    const float* __restrict__ w2, const float* __restrict__ b2,
    float* __restrict__ h2, int n)
{
    __shared__ float xs[64][68];
    __shared__ float ws[64][68];
    const int t = threadIdx.x;
    const int n0g = blockIdx.x * 64;
    const int nb = (t & 15) * 4, c0 = (t >> 4) * 4;
    float acc[4][4];
    #pragma unroll
    for (int a = 0; a < 4; ++a)
        #pragma unroll
        for (int b = 0; b < 4; ++b) acc[a][b] = 0.f;

    for (int kc = 0; kc < 2; ++kc) {
        __syncthreads();
        #pragma unroll
        for (int i = 0; i < 4; ++i) {
            const int idx = i * 256 + t;
            const int node = idx >> 4, kk = (idx & 15) * 4;
            int gn = n0g + node; if (gn >= n) gn = n - 1;
            const float4 v = *(const float4*)&h1[(size_t)gn * 128 + kc * 64 + kk];
            xs[kk][node] = v.x; xs[kk + 1][node] = v.y; xs[kk + 2][node] = v.z; xs[kk + 3][node] = v.w;
        }
        #pragma unroll
        for (int i = 0; i < 4; ++i) {
            const int idx = i * 256 + t;
            const int kk = idx >> 4, cc = (idx & 15) * 4;
            *(float4*)&ws[kk][cc] = *(const float4*)&w2[(size_t)(kc * 64 + kk) * 64 + cc];
        }
        __syncthreads();
        #pragma unroll 4
        for (int kk = 0; kk < 64; ++kk) {
            const float4 xv = *(const float4*)&xs[kk][nb];
            const float4 wa = *(const float4*)&ws[kk][c0];
            const float xr[4] = {xv.x, xv.y, xv.z, xv.w};
            const float wr[4] = {wa.x, wa.y, wa.z, wa.w};
            #pragma unroll
            for (int a = 0; a < 4; ++a)
                #pragma unroll
                for (int b = 0; b < 4; ++b) acc[a][b] = fmaf(xr[a], wr[b], acc[a][b]);
        }
    }
    float bb[4];
    #pragma unroll
    for (int b = 0; b < 4; ++b) bb[b] = b2[c0 + b];
    #pragma unroll
    for (int a = 0; a < 4; ++a) {
        const int gn = n0g + nb + a;
        if (gn < n) {
            float4 o;
            o.x = fmaxf(acc[a][0] + bb[0], 0.f); o.y = fmaxf(acc[a][1] + bb[1], 0.f);
            o.z = fmaxf(acc[a][2] + bb[2], 0.f); o.w = fmaxf(acc[a][3] + bb[3], 0.f);
            *(float4*)&h2[(size_t)gn * 64 + c0] = o;
        }
    }
}

// G3: hg1 = h2 @ g1w ; a1s/a1d per (node,head).  h2:[N,64] g1w:[64,256]  tile 32x256, K-chunk 32
__global__ __launch_bounds__(256) void k_g1feat(const float* __restrict__ h2,
    const float* __restrict__ w, const float* __restrict__ attS, const float* __restrict__ attD,
    float* __restrict__ hg1, float* __restrict__ a1s, float* __restrict__ a1d, int n)
{
    __shared__ float xs[32][36];
    __shared__ float ws[32][260];
    __shared__ float as[32][4], ad[32][4];
    const int t = threadIdx.x;
    const int n0g = blockIdx.x * 32;
    const int nb = (t & 7) * 4, c0 = (t >> 3) * 8;
    if (t < 128) { ((float*)as)[t] = 0.f; ((float*)ad)[t] = 0.f; }
    float acc[4][8];
    #pragma unroll
    for (int a = 0; a < 4; ++a)
        #pragma unroll
        for (int b = 0; b < 8; ++b) acc[a][b] = 0.f;

    for (int kc = 0; kc < 2; ++kc) {
        __syncthreads();
        {
            const int node = t >> 3, kk = (t & 7) * 4;
            int gn = n0g + node; if (gn >= n) gn = n - 1;
            const float4 v = *(const float4*)&h2[(size_t)gn * 64 + kc * 32 + kk];
            xs[kk][node] = v.x; xs[kk + 1][node] = v.y; xs[kk + 2][node] = v.z; xs[kk + 3][node] = v.w;
        }
        #pragma unroll
        for (int i = 0; i < 8; ++i) {
            const int idx = i * 256 + t;
            const int kk = idx >> 6, cc = (idx & 63) * 4;
            *(float4*)&ws[kk][cc] = *(const float4*)&w[(size_t)(kc * 32 + kk) * 256 + cc];
        }
        __syncthreads();
        #pragma unroll 4
        for (int kk = 0; kk < 32; ++kk) {
            const float4 xv = *(const float4*)&xs[kk][nb];
            const float4 wa = *(const float4*)&ws[kk][c0];
            const float4 wb = *(const float4*)&ws[kk][c0 + 4];
            const float xr[4] = {xv.x, xv.y, xv.z, xv.w};
            const float wr[8] = {wa.x, wa.y, wa.z, wa.w, wb.x, wb.y, wb.z, wb.w};
            #pragma unroll
            for (int a = 0; a < 4; ++a)
                #pragma unroll
                for (int b = 0; b < 8; ++b) acc[a][b] = fmaf(xr[a], wr[b], acc[a][b]);
        }
    }
    // store hg1 + attention partials
    const int head = c0 >> 6;
    float asr[8], adr[8];
    #pragma unroll
    for (int b = 0; b < 8; ++b) { asr[b] = attS[c0 + b]; adr[b] = attD[c0 + b]; }
    #pragma unroll
    for (int a = 0; a < 4; ++a) {
        const int gn = n0g + nb + a;
        float ps = 0.f, pd = 0.f;
        #pragma unroll
        for (int b = 0; b < 8; ++b) { ps = fmaf(acc[a][b], asr[b], ps); pd = fmaf(acc[a][b], adr[b], pd); }
        atomicAdd(&as[nb + a][head], ps);
        atomicAdd(&ad[nb + a][head], pd);
        if (gn < n) {
            float4 o0 = {acc[a][0], acc[a][1], acc[a][2], acc[a][3]};
            float4 o1 = {acc[a][4], acc[a][5], acc[a][6], acc[a][7]};
            *(float4*)&hg1[(size_t)gn * 256 + c0] = o0;
            *(float4*)&hg1[(size_t)gn * 256 + c0 + 4] = o1;
        }
    }
    __syncthreads();
    if (t < 128) {
        const int node = t >> 2, h = t & 3;
        const int gn = n0g + node;
        if (gn < n) { a1s[gn * 4 + h] = as[node][h]; a1d[gn * 4 + h] = ad[node][h]; }
    }
}

// G4: hg2 = elu(norm(out1)) @ g2w ; a2s/a2d.  out1:[N,256] g2w:[256,32]  tile 64x32, K-chunk 64
__global__ __launch_bounds__(256) void k_g2feat(const float* __restrict__ out1,
    const float* __restrict__ cscale, const float* __restrict__ cshift,
    const float* __restrict__ w, const float* __restrict__ attS, const float* __restrict__ attD,
    float* __restrict__ hg2, float* __restrict__ a2s, float* __restrict__ a2d, int n)
{
    __shared__ float xs[64][68];
    __shared__ float ws[64][36];
    __shared__ float as[64], ad[64];
    const int t = threadIdx.x;
    const int n0g = blockIdx.x * 64;
    const int nb = (t & 15) * 4, c0 = (t >> 4) * 2;
    if (t < 64) { as[t] = 0.f; ad[t] = 0.f; }
    float acc[4][2];
    #pragma unroll
    for (int a = 0; a < 4; ++a) { acc[a][0] = 0.f; acc[a][1] = 0.f; }

    for (int kc = 0; kc < 4; ++kc) {
        __syncthreads();
        #pragma unroll
        for (int i = 0; i < 4; ++i) {
            const int idx = i * 256 + t;
            const int node = idx >> 4, kk = (idx & 15) * 4;
            int gn = n0g + node; if (gn >= n) gn = n - 1;
            float4 v = *(const float4*)&out1[(size_t)gn * 256 + kc * 64 + kk];
            const float4 sc = *(const float4*)&cscale[kc * 64 + kk];
            const float4 sh = *(const float4*)&cshift[kc * 64 + kk];
            v.x = v.x * sc.x + sh.x; v.y = v.y * sc.y + sh.y;
            v.z = v.z * sc.z + sh.z; v.w = v.w * sc.w + sh.w;
            v.x = v.x > 0.f ? v.x : __expf(v.x) - 1.f;
            v.y = v.y > 0.f ? v.y : __expf(v.y) - 1.f;
            v.z = v.z > 0.f ? v.z : __expf(v.z) - 1.f;
            v.w = v.w > 0.f ? v.w : __expf(v.w) - 1.f;
            xs[kk][node] = v.x; xs[kk + 1][node] = v.y; xs[kk + 2][node] = v.z; xs[kk + 3][node] = v.w;
        }
        #pragma unroll
        for (int i = 0; i < 2; ++i) {
            const int idx = i * 256 + t;
            const int kk = idx >> 3, cc = (idx & 7) * 4;
            *(float4*)&ws[kk][cc] = *(const float4*)&w[(size_t)(kc * 64 + kk) * 32 + cc];
        }
        __syncthreads();
        #pragma unroll 8
        for (int kk = 0; kk < 64; ++kk) {
            const float4 xv = *(const float4*)&xs[kk][nb];
            const float2 wa = *(const float2*)&ws[kk][c0];
            const float xr[4] = {xv.x, xv.y, xv.z, xv.w};
            #pragma unroll
            for (int a = 0; a < 4; ++a) {
                acc[a][0] = fmaf(xr[a], wa.x, acc[a][0]);
                acc[a][1] = fmaf(xr[a], wa.y, acc[a][1]);
            }
        }
    }
    const float s0 = attS[c0], s1 = attS[c0 + 1], d0 = attD[c0], d1 = attD[c0 + 1];
    #pragma unroll
    for (int a = 0; a < 4; ++a) {
        const int gn = n0g + nb + a;
        atomicAdd(&as[nb + a], acc[a][0] * s0 + acc[a][1] * s1);
        atomicAdd(&ad[nb + a], acc[a][0] * d0 + acc[a][1] * d1);
        if (gn < n) {
            float2 o = {acc[a][0], acc[a][1]};
            *(float2*)&hg2[(size_t)gn * 32 + c0] = o;
        }
    }
    __syncthreads();
    if (t < 64) {
        const int gn = n0g + t;
        if (gn < n) { a2s[gn] = as[t]; a2d[gn] = ad[t]; }
    }
}

// ---------------- CSR build ----------------
__global__ void k_hist(const int* __restrict__ dst, int* __restrict__ deg, int e) {
    int i = blockIdx.x * 256 + threadIdx.x;
    if (i < e) atomicAdd(&deg[dst[i]], 1);
}

__global__ __launch_bounds__(256) void k_scan1(const int* __restrict__ deg, int* __restrict__ offs,
                                               int* __restrict__ bsum, int n)
{
    __shared__ int sm[256];
    const int t = threadIdx.x;
    const int i = blockIdx.x * 256 + t;
    const int v = (i < n) ? deg[i] : 0;
    sm[t] = v;
    __syncthreads();
    for (int off = 1; off < 256; off <<= 1) {
        int add = (t >= off) ? sm[t - off] : 0;
        __syncthreads();
        sm[t] += add;
        __syncthreads();
    }
    if (i < n) offs[i] = sm[t] - v;
    if (t == 255) bsum[blockIdx.x] = sm[255];
}

__global__ __launch_bounds__(256) void k_scan2(int* __restrict__ bsum, int nb) {
    __shared__ int sm[256];
    const int t = threadIdx.x;
    const int v = (t < nb) ? bsum[t] : 0;
    sm[t] = v;
    __syncthreads();
    for (int off = 1; off < 256; off <<= 1) {
        int add = (t >= off) ? sm[t - off] : 0;
        __syncthreads();
        sm[t] += add;
        __syncthreads();
    }
    if (t < nb) bsum[t] = sm[t] - v;   // exclusive
}

__global__ void k_scan3(int* __restrict__ offs, int* __restrict__ cursor,
                        const int* __restrict__ bsum, int n, int e) {
    int i = blockIdx.x * 256 + threadIdx.x;
    if (i < n) {
        int o = offs[i] + bsum[i >> 8];
        offs[i] = o;
        cursor[i] = o;
    }
    if (i == 0) offs[n] = e;
}

__global__ void k_scatter(const int* __restrict__ src, const int* __restrict__ dst,
                          int* __restrict__ cursor, int* __restrict__ csr, int e) {
    int i = blockIdx.x * 256 + threadIdx.x;
    if (i < e) {
        int p = atomicAdd(&cursor[dst[i]], 1);
        csr[p] = src[i];
    }
}

// ---------------- GAT1 aggregation (online segment softmax + weighted sum) ----------------
__global__ __launch_bounds__(256) void k_gat1_agg(
    const float* __restrict__ hg1, const float* __restrict__ a1s, const float* __restrict__ a1d,
    const int* __restrict__ offs, const int* __restrict__ csr,
    const float* __restrict__ bias, float* __restrict__ out1)
{
    const int d = blockIdx.x, t = threadIdx.x;
    const int start = offs[d], end = offs[d + 1];
    const float4* __restrict__ a1s4 = (const float4*)a1s;
    const float4 adv = ((const float4*)a1d)[d];
    const float ad[4] = {adv.x, adv.y, adv.z, adv.w};

    float m[4], s[4];
    #pragma unroll
    for (int h = 0; h < 4; ++h) { m[h] = -1e30f; s[h] = 0.f; }
    for (int e = start + t; e < end; e += 256) {
        const int sid = csr[e];
        const float4 av = a1s4[sid];
        const float lv[4] = {av.x + ad[0], av.y + ad[1], av.z + ad[2], av.w + ad[3]};
        #pragma unroll
        for (int h = 0; h < 4; ++h) {
            float l = lrelu(lv[h]);
            float nm = fmaxf(m[h], l);
            s[h] = s[h] * __expf(m[h] - nm) + __expf(l - nm);
            m[h] = nm;
        }
    }
    for (int off = 32; off; off >>= 1) {
        #pragma unroll
        for (int h = 0; h < 4; ++h) {
            float om = __shfl_down(m[h], off), os = __shfl_down(s[h], off);
            float nm = fmaxf(m[h], om);
            s[h] = s[h] * __expf(m[h] - nm) + os * __expf(om - nm);
            m[h] = nm;
        }
    }
    __shared__ float wm[4][4], wsd[4][4];
    __shared__ float fm[4], finv[4];
    const int wave = t >> 6;
    if ((t & 63) == 0) {
        #pragma unroll
        for (int h = 0; h < 4; ++h) { wm[wave][h] = m[h]; wsd[wave][h] = s[h]; }
    }
    __syncthreads();
    if (t == 0) {
        #pragma unroll
        for (int h = 0; h < 4; ++h) {
            float M = wm[0][h], S = wsd[0][h];
            for (int w = 1; w < 4; ++w) {
                float nm = fmaxf(M, wm[w][h]);
                S = S * __expf(M - nm) + wsd[w][h] * __expf(wm[w][h] - nm);
                M = nm;
            }
            fm[h] = M;
            finv[h] = 1.f / (S + 1e-16f);
        }
    }
    __syncthreads();

    __shared__ int sidL[64];
    __shared__ float alphaL[64][4];
    const int head = t >> 6;
    float acc = 0.f;
    for (int base = start; base < end; base += 64) {
        const int cnt = min(64, end - base);
        if (t < cnt) {
            const int sid = csr[base + t];
            sidL[t] = sid;
            const float4 av = a1s4[sid];
            const float lv[4] = {av.x + ad[0], av.y + ad[1], av.z + ad[2], av.w + ad[3]};
            #pragma unroll
            for (int h = 0; h < 4; ++h)
                alphaL[t][h] = __expf(lrelu(lv[h]) - fm[h]) * finv[h];
        }
        __syncthreads();
        for (int i = 0; i < cnt; ++i)
            acc = fmaf(alphaL[i][head], hg1[(size_t)sidL[i] * 256 + t], acc);
        __syncthreads();
    }
    out1[(size_t)d * 256 + t] = acc + bias[t];
}

// ---------------- GraphNorm ----------------
__global__ __launch_bounds__(256) void k_colstat(const float* __restrict__ out1,
    float* __restrict__ colsum, float* __restrict__ colsq, int n)
{
    const int t = threadIdx.x;
    float s = 0.f, q = 0.f;
    for (int r = blockIdx.x; r < n; r += gridDim.x) {
        float v = out1[(size_t)r * 256 + t];
        s += v;
        q += v * v;
    }
    atomicAdd(&colsum[t], s);
    atomicAdd(&colsq[t], q);
}

__global__ void k_norm_params(const float* __restrict__ colsum, const float* __restrict__ colsq,
    const float* __restrict__ gw, const float* __restrict__ gb, const float* __restrict__ gms,
    float* __restrict__ scale, float* __restrict__ shift, int n)
{
    const int t = threadIdx.x;
    const float invn = 1.f / (float)n;
    const float mean = colsum[t] * invn;
    const float msq = colsq[t] * invn;
    const float ms = gms[t];
    const float var = msq - 2.f * ms * mean * mean + ms * ms * mean * mean;
    const float sc = gw[t] * rsqrtf(var + GEPS);
    scale[t] = sc;
    shift[t] = gb[t] - mean * ms * sc;
}

// ---------------- GAT2 aggregation + bias + log_softmax ----------------
__global__ __launch_bounds__(64) void k_gat2_agg(
    const float* __restrict__ hg2, const float* __restrict__ a2s, const float* __restrict__ a2d,
    const int* __restrict__ offs, const int* __restrict__ csr,
    const float* __restrict__ bias, float* __restrict__ out)
{
    const int d = blockIdx.x, t = threadIdx.x;
    const int start = offs[d], end = offs[d + 1];
    const float adv = a2d[d];
    float m = -1e30f, s = 0.f;
    for (int e = start + t; e < end; e += 64) {
        const int sid = csr[e];
        float l = lrelu(a2s[sid] + adv);
        float nm = fmaxf(m, l);
        s = s * __expf(m - nm) + __expf(l - nm);
        m = nm;
    }
    for (int off = 32; off; off >>= 1) {
        float om = __shfl_xor(m, off), os = __shfl_xor(s, off);
        float nm = fmaxf(m, om);
        s = s * __expf(m - nm) + os * __expf(om - nm);
        m = nm;
    }
    const float inv = 1.f / (s + 1e-16f);

    __shared__ int sidL[64];
    __shared__ float alphaL[64];
    const int c = t & 31, half = t >> 5;
    float acc = 0.f;
    for (int base = start; base < end; base += 64) {
        const int cnt = min(64, end - base);
        if (t < cnt) {
            const int sid = csr[base + t];
            sidL[t] = sid;
            alphaL[t] = __expf(lrelu(a2s[sid] + adv) - m) * inv;
        }
        __syncthreads();
        for (int i = half; i < cnt; i += 2)
            acc = fmaf(alphaL[i], hg2[(size_t)sidL[i] * 32 + c], acc);
        __syncthreads();
    }
    acc += __shfl_xor(acc, 32);
    const float v = acc + bias[c];
    float mx = v;
    for (int off = 16; off; off >>= 1) mx = fmaxf(mx, __shfl_xor(mx, off, 32));
    float se = __expf(v - mx);
    for (int off = 16; off; off >>= 1) se += __shfl_xor(se, off, 32);
    if (t < 32) out[(size_t)d * 32 + t] = v - mx - __logf(se);
}

// ---------------- launcher ----------------
extern "C" void kernel_launch(void* const* d_in, const int* in_sizes, int n_in,
                              void* d_out, int out_size, void* d_ws, size_t ws_size,
                              hipStream_t stream)
{
    const float* x    = (const float*)d_in[0];
    const int*   ei   = (const int*)d_in[1];
    const float* t1w  = (const float*)d_in[2];
    const float* t1b  = (const float*)d_in[3];
    const float* t2w  = (const float*)d_in[4];
    const float* t2b  = (const float*)d_in[5];
    const float* g1w  = (const float*)d_in[6];
    const float* g1as = (const float*)d_in[7];
    const float* g1ad = (const float*)d_in[8];
    const float* g1b  = (const float*)d_in[9];
    const float* gnw  = (const float*)d_in[10];
    const float* gnb  = (const float*)d_in[11];
    const float* gnms = (const float*)d_in[12];
    const float* g2w  = (const float*)d_in[13];
    const float* g2as = (const float*)d_in[14];
    const float* g2ad = (const float*)d_in[15];
    const float* g2b  = (const float*)d_in[16];

    const int N = in_sizes[0] / 256;
    const int E = in_sizes[1] / 2;
    const int* srcA = ei;
    const int* dstA = ei + E;

    char* ws = (char*)d_ws;
    size_t cur = 0;
    auto alloc = [&](size_t bytes) -> char* {
        char* p = ws + cur;
        cur += (bytes + 255) & ~(size_t)255;
        return p;
    };
    float* h2     = (float*)alloc((size_t)N * 64 * 4);
    float* hg1    = (float*)alloc((size_t)N * 256 * 4);
    float* a1s    = (float*)alloc((size_t)N * 4 * 4);
    float* a1d    = (float*)alloc((size_t)N * 4 * 4);
    float* out1   = (float*)alloc((size_t)N * 256 * 4);
    float* hg2    = (float*)alloc((size_t)N * 32 * 4);
    float* a2s    = (float*)alloc((size_t)N * 4);
    float* a2d    = (float*)alloc((size_t)N * 4);
    int*   deg    = (int*)alloc((size_t)(N + 1) * 4);
    int*   offs   = (int*)alloc((size_t)(N + 1) * 4);
    int*   cursor = (int*)alloc((size_t)N * 4);
    int*   bsum   = (int*)alloc(1024);
    int*   csr    = (int*)alloc((size_t)E * 4);
    float* colsum = (float*)alloc(1024);
    float* colsq  = (float*)alloc(1024);
    float* cscale = (float*)alloc(1024);
    float* cshift = (float*)alloc(1024);

    // h1 [N,128] is only live between k_lin1 and k_lin2 -> alias onto out1 buffer ([N,256])
    float* h1 = out1;

    hipMemsetAsync(deg, 0, (size_t)(N + 1) * 4, stream);
    hipMemsetAsync(colsum, 0, 2048, stream);

    const int EB = (E + 255) / 256;
    const int NB = (N + 255) / 256;
    const int B64 = (N + 63) / 64;
    const int B32 = (N + 31) / 32;

    k_lin1<<<B64, 256, 0, stream>>>(x, t1w, t1b, h1, N);
    k_lin2<<<B64, 256, 0, stream>>>(h1, t2w, t2b, h2, N);
    k_g1feat<<<B32, 256, 0, stream>>>(h2, g1w, g1as, g1ad, hg1, a1s, a1d, N);
    k_hist<<<EB, 256, 0, stream>>>(dstA, deg, E);
    k_scan1<<<NB, 256, 0, stream>>>(deg, offs, bsum, N);
    k_scan2<<<1, 256, 0, stream>>>(bsum, NB);
    k_scan3<<<NB, 256, 0, stream>>>(offs, cursor, bsum, N, E);
    k_scatter<<<EB, 256, 0, stream>>>(srcA, dstA, cursor, csr, E);
    k_gat1_agg<<<N, 256, 0, stream>>>(hg1, a1s, a1d, offs, csr, g1b, out1);
    k_colstat<<<256, 256, 0, stream>>>(out1, colsum, colsq, N);
    k_norm_params<<<1, 256, 0, stream>>>(colsum, colsq, gnw, gnb, gnms, cscale, cshift, N);
    k_g2feat<<<B64, 256, 0, stream>>>(out1, cscale, cshift, g2w, g2as, g2ad, hg2, a2s, a2d, N);
    k_gat2_agg<<<N, 64, 0, stream>>>(hg2, a2s, a2d, offs, csr, g2b, (float*)d_out);
}

// Round 3
// 439.947 us; speedup vs baseline: 1.7498x; 1.1926x over previous
//
#include <hip/hip_runtime.h>

#define NSLOPE 0.2f
#define GEPS 1e-5f

typedef unsigned short ushortT;
typedef __attribute__((ext_vector_type(8))) unsigned short us8;

__device__ __forceinline__ float lrelu(float x) { return x >= 0.f ? x : NSLOPE * x; }
__device__ __forceinline__ ushortT f2bf(float f) {
    unsigned int u = __float_as_uint(f);
    return (ushortT)((u + 0x7fffu + ((u >> 16) & 1u)) >> 16);
}
__device__ __forceinline__ float bf2f(ushortT h) {
    return __uint_as_float((unsigned int)h << 16);
}

// =================== dense transforms: LDS-staged register-blocked GEMMs ===================

// G1: h1 = relu(x @ w1 + b1)   x:[N,256] w1:[256,128]  tile 64x128, K-chunk 64
__global__ __launch_bounds__(256) void k_lin1(const float* __restrict__ x,
    const float* __restrict__ w1, const float* __restrict__ b1,
    float* __restrict__ h1, int n)
{
    __shared__ float xs[64][68];
    __shared__ float ws[64][132];
    const int t = threadIdx.x;
    const int n0g = blockIdx.x * 64;
    const int nb = (t & 15) * 4, c0 = (t >> 4) * 8;
    float acc[4][8];
    #pragma unroll
    for (int a = 0; a < 4; ++a)
        #pragma unroll
        for (int b = 0; b < 8; ++b) acc[a][b] = 0.f;

    for (int kc = 0; kc < 4; ++kc) {
        __syncthreads();
        #pragma unroll
        for (int i = 0; i < 4; ++i) {
            const int idx = i * 256 + t;
            const int node = idx >> 4, kk = (idx & 15) * 4;
            int gn = n0g + node; if (gn >= n) gn = n - 1;
            const float4 v = *(const float4*)&x[(size_t)gn * 256 + kc * 64 + kk];
            xs[kk][node] = v.x; xs[kk + 1][node] = v.y; xs[kk + 2][node] = v.z; xs[kk + 3][node] = v.w;
        }
        #pragma unroll
        for (int i = 0; i < 8; ++i) {
            const int idx = i * 256 + t;
            const int kk = idx >> 5, cc = (idx & 31) * 4;
            *(float4*)&ws[kk][cc] = *(const float4*)&w1[(size_t)(kc * 64 + kk) * 128 + cc];
        }
        __syncthreads();
        #pragma unroll 4
        for (int kk = 0; kk < 64; ++kk) {
            const float4 xv = *(const float4*)&xs[kk][nb];
            const float4 wa = *(const float4*)&ws[kk][c0];
            const float4 wb = *(const float4*)&ws[kk][c0 + 4];
            const float xr[4] = {xv.x, xv.y, xv.z, xv.w};
            const float wr[8] = {wa.x, wa.y, wa.z, wa.w, wb.x, wb.y, wb.z, wb.w};
            #pragma unroll
            for (int a = 0; a < 4; ++a)
                #pragma unroll
                for (int b = 0; b < 8; ++b) acc[a][b] = fmaf(xr[a], wr[b], acc[a][b]);
        }
    }
    float bb[8];
    #pragma unroll
    for (int b = 0; b < 8; ++b) bb[b] = b1[c0 + b];
    #pragma unroll
    for (int a = 0; a < 4; ++a) {
        const int gn = n0g + nb + a;
        if (gn < n) {
            float4 o0, o1;
            o0.x = fmaxf(acc[a][0] + bb[0], 0.f); o0.y = fmaxf(acc[a][1] + bb[1], 0.f);
            o0.z = fmaxf(acc[a][2] + bb[2], 0.f); o0.w = fmaxf(acc[a][3] + bb[3], 0.f);
            o1.x = fmaxf(acc[a][4] + bb[4], 0.f); o1.y = fmaxf(acc[a][5] + bb[5], 0.f);
            o1.z = fmaxf(acc[a][6] + bb[6], 0.f); o1.w = fmaxf(acc[a][7] + bb[7], 0.f);
            *(float4*)&h1[(size_t)gn * 128 + c0] = o0;
            *(float4*)&h1[(size_t)gn * 128 + c0 + 4] = o1;
        }
    }
}

// G2: h2 = relu(h1 @ w2 + b2)  h1:[N,128] w2:[128,64]  tile 64x64
__global__ __launch_bounds__(256) void k_lin2(const float* __restrict__ h1,
    const float* __restrict__ w2, const float* __restrict__ b2,
    float* __restrict__ h2, int n)
{
    __shared__ float xs[64][68];
    __shared__ float ws[64][68];
    const int t = threadIdx.x;
    const int n0g = blockIdx.x * 64;
    const int nb = (t & 15) * 4, c0 = (t >> 4) * 4;
    float acc[4][4];
    #pragma unroll
    for (int a = 0; a < 4; ++a)
        #pragma unroll
        for (int b = 0; b < 4; ++b) acc[a][b] = 0.f;

    for (int kc = 0; kc < 2; ++kc) {
        __syncthreads();
        #pragma unroll
        for (int i = 0; i < 4; ++i) {
            const int idx = i * 256 + t;
            const int node = idx >> 4, kk = (idx & 15) * 4;
            int gn = n0g + node; if (gn >= n) gn = n - 1;
            const float4 v = *(const float4*)&h1[(size_t)gn * 128 + kc * 64 + kk];
            xs[kk][node] = v.x; xs[kk + 1][node] = v.y; xs[kk + 2][node] = v.z; xs[kk + 3][node] = v.w;
        }
        #pragma unroll
        for (int i = 0; i < 4; ++i) {
            const int idx = i * 256 + t;
            const int kk = idx >> 4, cc = (idx & 15) * 4;
            *(float4*)&ws[kk][cc] = *(const float4*)&w2[(size_t)(kc * 64 + kk) * 64 + cc];
        }
        __syncthreads();
        #pragma unroll 4
        for (int kk = 0; kk < 64; ++kk) {
            const float4 xv = *(const float4*)&xs[kk][nb];
            const float4 wa = *(const float4*)&ws[kk][c0];
            const float xr[4] = {xv.x, xv.y, xv.z, xv.w};
            const float wr[4] = {wa.x, wa.y, wa.z, wa.w};
            #pragma unroll
            for (int a = 0; a < 4; ++a)
                #pragma unroll
                for (int b = 0; b < 4; ++b) acc[a][b] = fmaf(xr[a], wr[b], acc[a][b]);
        }
    }
    float bb[4];
    #pragma unroll
    for (int b = 0; b < 4; ++b) bb[b] = b2[c0 + b];
    #pragma unroll
    for (int a = 0; a < 4; ++a) {
        const int gn = n0g + nb + a;
        if (gn < n) {
            float4 o;
            o.x = fmaxf(acc[a][0] + bb[0], 0.f); o.y = fmaxf(acc[a][1] + bb[1], 0.f);
            o.z = fmaxf(acc[a][2] + bb[2], 0.f); o.w = fmaxf(acc[a][3] + bb[3], 0.f);
            *(float4*)&h2[(size_t)gn * 64 + c0] = o;
        }
    }
}

// G3: hg1(bf16) = h2 @ g1w ; a1s/a1d per (node,head)
__global__ __launch_bounds__(256) void k_g1feat(const float* __restrict__ h2,
    const float* __restrict__ w, const float* __restrict__ attS, const float* __restrict__ attD,
    ushortT* __restrict__ hg1, float* __restrict__ a1s, float* __restrict__ a1d, int n)
{
    __shared__ float xs[32][36];
    __shared__ float ws[32][260];
    __shared__ float as[32][4], ad[32][4];
    const int t = threadIdx.x;
    const int n0g = blockIdx.x * 32;
    const int nb = (t & 7) * 4, c0 = (t >> 3) * 8;
    if (t < 128) { ((float*)as)[t] = 0.f; ((float*)ad)[t] = 0.f; }
    float acc[4][8];
    #pragma unroll
    for (int a = 0; a < 4; ++a)
        #pragma unroll
        for (int b = 0; b < 8; ++b) acc[a][b] = 0.f;

    for (int kc = 0; kc < 2; ++kc) {
        __syncthreads();
        {
            const int node = t >> 3, kk = (t & 7) * 4;
            int gn = n0g + node; if (gn >= n) gn = n - 1;
            const float4 v = *(const float4*)&h2[(size_t)gn * 64 + kc * 32 + kk];
            xs[kk][node] = v.x; xs[kk + 1][node] = v.y; xs[kk + 2][node] = v.z; xs[kk + 3][node] = v.w;
        }
        #pragma unroll
        for (int i = 0; i < 8; ++i) {
            const int idx = i * 256 + t;
            const int kk = idx >> 6, cc = (idx & 63) * 4;
            *(float4*)&ws[kk][cc] = *(const float4*)&w[(size_t)(kc * 32 + kk) * 256 + cc];
        }
        __syncthreads();
        #pragma unroll 4
        for (int kk = 0; kk < 32; ++kk) {
            const float4 xv = *(const float4*)&xs[kk][nb];
            const float4 wa = *(const float4*)&ws[kk][c0];
            const float4 wb = *(const float4*)&ws[kk][c0 + 4];
            const float xr[4] = {xv.x, xv.y, xv.z, xv.w};
            const float wr[8] = {wa.x, wa.y, wa.z, wa.w, wb.x, wb.y, wb.z, wb.w};
            #pragma unroll
            for (int a = 0; a < 4; ++a)
                #pragma unroll
                for (int b = 0; b < 8; ++b) acc[a][b] = fmaf(xr[a], wr[b], acc[a][b]);
        }
    }
    const int head = c0 >> 6;
    float asr[8], adr[8];
    #pragma unroll
    for (int b = 0; b < 8; ++b) { asr[b] = attS[c0 + b]; adr[b] = attD[c0 + b]; }
    #pragma unroll
    for (int a = 0; a < 4; ++a) {
        const int gn = n0g + nb + a;
        float ps = 0.f, pd = 0.f;
        #pragma unroll
        for (int b = 0; b < 8; ++b) { ps = fmaf(acc[a][b], asr[b], ps); pd = fmaf(acc[a][b], adr[b], pd); }
        atomicAdd(&as[nb + a][head], ps);
        atomicAdd(&ad[nb + a][head], pd);
        if (gn < n) {
            us8 o;
            #pragma unroll
            for (int b = 0; b < 8; ++b) o[b] = f2bf(acc[a][b]);
            *(us8*)&hg1[(size_t)gn * 256 + c0] = o;
        }
    }
    __syncthreads();
    if (t < 128) {
        const int node = t >> 2, h = t & 3;
        const int gn = n0g + node;
        if (gn < n) { a1s[gn * 4 + h] = as[node][h]; a1d[gn * 4 + h] = ad[node][h]; }
    }
}

// G4: hg2(bf16) = elu(norm(out1)) @ g2w ; a2s/a2d
__global__ __launch_bounds__(256) void k_g2feat(const float* __restrict__ out1,
    const float* __restrict__ cscale, const float* __restrict__ cshift,
    const float* __restrict__ w, const float* __restrict__ attS, const float* __restrict__ attD,
    ushortT* __restrict__ hg2, float* __restrict__ a2s, float* __restrict__ a2d, int n)
{
    __shared__ float xs[64][68];
    __shared__ float ws[64][36];
    __shared__ float as[64], ad[64];
    const int t = threadIdx.x;
    const int n0g = blockIdx.x * 64;
    const int nb = (t & 15) * 4, c0 = (t >> 4) * 2;
    if (t < 64) { as[t] = 0.f; ad[t] = 0.f; }
    float acc[4][2];
    #pragma unroll
    for (int a = 0; a < 4; ++a) { acc[a][0] = 0.f; acc[a][1] = 0.f; }

    for (int kc = 0; kc < 4; ++kc) {
        __syncthreads();
        #pragma unroll
        for (int i = 0; i < 4; ++i) {
            const int idx = i * 256 + t;
            const int node = idx >> 4, kk = (idx & 15) * 4;
            int gn = n0g + node; if (gn >= n) gn = n - 1;
            float4 v = *(const float4*)&out1[(size_t)gn * 256 + kc * 64 + kk];
            const float4 sc = *(const float4*)&cscale[kc * 64 + kk];
            const float4 sh = *(const float4*)&cshift[kc * 64 + kk];
            v.x = v.x * sc.x + sh.x; v.y = v.y * sc.y + sh.y;
            v.z = v.z * sc.z + sh.z; v.w = v.w * sc.w + sh.w;
            v.x = v.x > 0.f ? v.x : __expf(v.x) - 1.f;
            v.y = v.y > 0.f ? v.y : __expf(v.y) - 1.f;
            v.z = v.z > 0.f ? v.z : __expf(v.z) - 1.f;
            v.w = v.w > 0.f ? v.w : __expf(v.w) - 1.f;
            xs[kk][node] = v.x; xs[kk + 1][node] = v.y; xs[kk + 2][node] = v.z; xs[kk + 3][node] = v.w;
        }
        #pragma unroll
        for (int i = 0; i < 2; ++i) {
            const int idx = i * 256 + t;
            const int kk = idx >> 3, cc = (idx & 7) * 4;
            *(float4*)&ws[kk][cc] = *(const float4*)&w[(size_t)(kc * 64 + kk) * 32 + cc];
        }
        __syncthreads();
        #pragma unroll 8
        for (int kk = 0; kk < 64; ++kk) {
            const float4 xv = *(const float4*)&xs[kk][nb];
            const float2 wa = *(const float2*)&ws[kk][c0];
            const float xr[4] = {xv.x, xv.y, xv.z, xv.w};
            #pragma unroll
            for (int a = 0; a < 4; ++a) {
                acc[a][0] = fmaf(xr[a], wa.x, acc[a][0]);
                acc[a][1] = fmaf(xr[a], wa.y, acc[a][1]);
            }
        }
    }
    const float s0 = attS[c0], s1 = attS[c0 + 1], d0 = attD[c0], d1 = attD[c0 + 1];
    #pragma unroll
    for (int a = 0; a < 4; ++a) {
        const int gn = n0g + nb + a;
        atomicAdd(&as[nb + a], acc[a][0] * s0 + acc[a][1] * s1);
        atomicAdd(&ad[nb + a], acc[a][0] * d0 + acc[a][1] * d1);
        if (gn < n) {
            ushort2 o = {f2bf(acc[a][0]), f2bf(acc[a][1])};
            *(ushort2*)&hg2[(size_t)gn * 32 + c0] = o;
        }
    }
    __syncthreads();
    if (t < 64) {
        const int gn = n0g + t;
        if (gn < n) { a2s[gn] = as[t]; a2d[gn] = ad[t]; }
    }
}

// ---------------- CSR build ----------------
__global__ void k_hist(const int* __restrict__ dst, int* __restrict__ deg, int e) {
    int i = blockIdx.x * 256 + threadIdx.x;
    if (i < e) atomicAdd(&deg[dst[i]], 1);
}

__global__ __launch_bounds__(256) void k_scan1(const int* __restrict__ deg, int* __restrict__ offs,
                                               int* __restrict__ bsum, int n)
{
    __shared__ int sm[256];
    const int t = threadIdx.x;
    const int i = blockIdx.x * 256 + t;
    const int v = (i < n) ? deg[i] : 0;
    sm[t] = v;
    __syncthreads();
    for (int off = 1; off < 256; off <<= 1) {
        int add = (t >= off) ? sm[t - off] : 0;
        __syncthreads();
        sm[t] += add;
        __syncthreads();
    }
    if (i < n) offs[i] = sm[t] - v;
    if (t == 255) bsum[blockIdx.x] = sm[255];
}

__global__ __launch_bounds__(256) void k_scan2(int* __restrict__ bsum, int nb) {
    __shared__ int sm[256];
    const int t = threadIdx.x;
    const int v = (t < nb) ? bsum[t] : 0;
    sm[t] = v;
    __syncthreads();
    for (int off = 1; off < 256; off <<= 1) {
        int add = (t >= off) ? sm[t - off] : 0;
        __syncthreads();
        sm[t] += add;
        __syncthreads();
    }
    if (t < nb) bsum[t] = sm[t] - v;
}

__global__ void k_scan3(int* __restrict__ offs, int* __restrict__ cursor,
                        const int* __restrict__ bsum, int n, int e) {
    int i = blockIdx.x * 256 + threadIdx.x;
    if (i < n) {
        int o = offs[i] + bsum[i >> 8];
        offs[i] = o;
        cursor[i] = o;
    }
    if (i == 0) offs[n] = e;
}

__global__ void k_scatter(const int* __restrict__ src, const int* __restrict__ dst,
                          int* __restrict__ cursor, int* __restrict__ csr, int e) {
    int i = blockIdx.x * 256 + threadIdx.x;
    if (i < e) {
        int p = atomicAdd(&cursor[dst[i]], 1);
        csr[p] = src[i];
    }
}

// ---------------- GAT1 aggregation: wave-per-node, shfl softmax, bf16 gather ----------------
__global__ __launch_bounds__(256) void k_gat1_agg(
    const ushortT* __restrict__ hg1, const float* __restrict__ a1s, const float* __restrict__ a1d,
    const int* __restrict__ offs, const int* __restrict__ csr,
    const float* __restrict__ bias, float* __restrict__ out1, int n)
{
    const int lane = threadIdx.x & 63, wave = threadIdx.x >> 6;
    const int d = blockIdx.x * 4 + wave;
    if (d >= n) return;
    const int start = offs[d], end = offs[d + 1];
    const float4 adv = ((const float4*)a1d)[d];
    const float ad0 = adv.x, ad1 = adv.y, ad2 = adv.z, ad3 = adv.w;
    const float4* __restrict__ a1s4 = (const float4*)a1s;

    float m0 = -1e30f, m1 = -1e30f, m2 = -1e30f, m3 = -1e30f;
    float s0 = 0.f, s1 = 0.f, s2 = 0.f, s3 = 0.f;
    for (int e = start + lane; e < end; e += 64) {
        const float4 av = a1s4[csr[e]];
        const float l0 = lrelu(av.x + ad0), l1 = lrelu(av.y + ad1);
        const float l2 = lrelu(av.z + ad2), l3 = lrelu(av.w + ad3);
        float nm;
        nm = fmaxf(m0, l0); s0 = s0 * __expf(m0 - nm) + __expf(l0 - nm); m0 = nm;
        nm = fmaxf(m1, l1); s1 = s1 * __expf(m1 - nm) + __expf(l1 - nm); m1 = nm;
        nm = fmaxf(m2, l2); s2 = s2 * __expf(m2 - nm) + __expf(l2 - nm); m2 = nm;
        nm = fmaxf(m3, l3); s3 = s3 * __expf(m3 - nm) + __expf(l3 - nm); m3 = nm;
    }
    for (int off = 1; off < 64; off <<= 1) {
        float om, os, nm;
        om = __shfl_xor(m0, off); os = __shfl_xor(s0, off);
        nm = fmaxf(m0, om); s0 = s0 * __expf(m0 - nm) + os * __expf(om - nm); m0 = nm;
        om = __shfl_xor(m1, off); os = __shfl_xor(s1, off);
        nm = fmaxf(m1, om); s1 = s1 * __expf(m1 - nm) + os * __expf(om - nm); m1 = nm;
        om = __shfl_xor(m2, off); os = __shfl_xor(s2, off);
        nm = fmaxf(m2, om); s2 = s2 * __expf(m2 - nm) + os * __expf(om - nm); m2 = nm;
        om = __shfl_xor(m3, off); os = __shfl_xor(s3, off);
        nm = fmaxf(m3, om); s3 = s3 * __expf(m3 - nm) + os * __expf(om - nm); m3 = nm;
    }
    const float i0 = 1.f / (s0 + 1e-16f), i1 = 1.f / (s1 + 1e-16f);
    const float i2 = 1.f / (s2 + 1e-16f), i3 = 1.f / (s3 + 1e-16f);

    const int c = lane * 4;
    const int head = lane >> 4;
    float acc0 = 0.f, acc1 = 0.f, acc2 = 0.f, acc3 = 0.f;
    for (int base = start; base < end; base += 64) {
        const int cnt = min(64, end - base);
        int sid = 0; float a0 = 0.f, a1v = 0.f, a2v = 0.f, a3v = 0.f;
        if (lane < cnt) {
            sid = csr[base + lane];
            const float4 av = a1s4[sid];
            a0 = __expf(lrelu(av.x + ad0) - m0) * i0;
            a1v = __expf(lrelu(av.y + ad1) - m1) * i1;
            a2v = __expf(lrelu(av.z + ad2) - m2) * i2;
            a3v = __expf(lrelu(av.w + ad3) - m3) * i3;
        }
        for (int i = 0; i < cnt; ++i) {
            const int si = __shfl(sid, i);
            const float b0 = __shfl(a0, i), b1 = __shfl(a1v, i);
            const float b2 = __shfl(a2v, i), b3 = __shfl(a3v, i);
            const float al = head < 2 ? (head == 0 ? b0 : b1) : (head == 2 ? b2 : b3);
            const ushort4 hv = *(const ushort4*)&hg1[(size_t)si * 256 + c];
            acc0 = fmaf(al, bf2f(hv.x), acc0);
            acc1 = fmaf(al, bf2f(hv.y), acc1);
            acc2 = fmaf(al, bf2f(hv.z), acc2);
            acc3 = fmaf(al, bf2f(hv.w), acc3);
        }
    }
    const float4 bv = *(const float4*)&bias[c];
    float4 o = {acc0 + bv.x, acc1 + bv.y, acc2 + bv.z, acc3 + bv.w};
    *(float4*)&out1[(size_t)d * 256 + c] = o;
}

// ---------------- GraphNorm ----------------
__global__ __launch_bounds__(256) void k_colstat(const float* __restrict__ out1,
    float* __restrict__ colsum, float* __restrict__ colsq, int n)
{
    const int t = threadIdx.x;
    float s = 0.f, q = 0.f;
    for (int r = blockIdx.x; r < n; r += gridDim.x) {
        float v = out1[(size_t)r * 256 + t];
        s += v;
        q += v * v;
    }
    atomicAdd(&colsum[t], s);
    atomicAdd(&colsq[t], q);
}

__global__ void k_norm_params(const float* __restrict__ colsum, const float* __restrict__ colsq,
    const float* __restrict__ gw, const float* __restrict__ gb, const float* __restrict__ gms,
    float* __restrict__ scale, float* __restrict__ shift, int n)
{
    const int t = threadIdx.x;
    const float invn = 1.f / (float)n;
    const float mean = colsum[t] * invn;
    const float msq = colsq[t] * invn;
    const float ms = gms[t];
    const float var = msq - 2.f * ms * mean * mean + ms * ms * mean * mean;
    const float sc = gw[t] * rsqrtf(var + GEPS);
    scale[t] = sc;
    shift[t] = gb[t] - mean * ms * sc;
}

// ---------------- GAT2 aggregation: wave-per-node + log_softmax ----------------
__global__ __launch_bounds__(256) void k_gat2_agg(
    const ushortT* __restrict__ hg2, const float* __restrict__ a2s, const float* __restrict__ a2d,
    const int* __restrict__ offs, const int* __restrict__ csr,
    const float* __restrict__ bias, float* __restrict__ out, int n)
{
    const int lane = threadIdx.x & 63, wave = threadIdx.x >> 6;
    const int d = blockIdx.x * 4 + wave;
    if (d >= n) return;
    const int start = offs[d], end = offs[d + 1];
    const float adv = a2d[d];
    float m = -1e30f, s = 0.f;
    for (int e = start + lane; e < end; e += 64) {
        const float l = lrelu(a2s[csr[e]] + adv);
        const float nm = fmaxf(m, l);
        s = s * __expf(m - nm) + __expf(l - nm);
        m = nm;
    }
    for (int off = 1; off < 64; off <<= 1) {
        const float om = __shfl_xor(m, off), os = __shfl_xor(s, off);
        const float nm = fmaxf(m, om);
        s = s * __expf(m - nm) + os * __expf(om - nm);
        m = nm;
    }
    const float inv = 1.f / (s + 1e-16f);
    const int c = lane & 31, half = lane >> 5;
    float acc = 0.f;
    for (int base = start; base < end; base += 64) {
        const int cnt = min(64, end - base);
        int sid = 0; float al = 0.f;
        if (lane < cnt) {
            sid = csr[base + lane];
            al = __expf(lrelu(a2s[sid] + adv) - m) * inv;
        }
        for (int i = half; i < cnt; i += 2) {
            const int si = __shfl(sid, i);
            const float a = __shfl(al, i);
            acc = fmaf(a, bf2f(hg2[(size_t)si * 32 + c]), acc);
        }
    }
    acc += __shfl_xor(acc, 32);
    const float v = acc + bias[c];
    float mx = v;
    for (int off = 16; off; off >>= 1) mx = fmaxf(mx, __shfl_xor(mx, off, 32));
    float se = __expf(v - mx);
    for (int off = 16; off; off >>= 1) se += __shfl_xor(se, off, 32);
    if (lane < 32) out[(size_t)d * 32 + lane] = v - mx - __logf(se);
}

// ---------------- launcher ----------------
extern "C" void kernel_launch(void* const* d_in, const int* in_sizes, int n_in,
                              void* d_out, int out_size, void* d_ws, size_t ws_size,
                              hipStream_t stream)
{
    const float* x    = (const float*)d_in[0];
    const int*   ei   = (const int*)d_in[1];
    const float* t1w  = (const float*)d_in[2];
    const float* t1b  = (const float*)d_in[3];
    const float* t2w  = (const float*)d_in[4];
    const float* t2b  = (const float*)d_in[5];
    const float* g1w  = (const float*)d_in[6];
    const float* g1as = (const float*)d_in[7];
    const float* g1ad = (const float*)d_in[8];
    const float* g1b  = (const float*)d_in[9];
    const float* gnw  = (const float*)d_in[10];
    const float* gnb  = (const float*)d_in[11];
    const float* gnms = (const float*)d_in[12];
    const float* g2w  = (const float*)d_in[13];
    const float* g2as = (const float*)d_in[14];
    const float* g2ad = (const float*)d_in[15];
    const float* g2b  = (const float*)d_in[16];

    const int N = in_sizes[0] / 256;
    const int E = in_sizes[1] / 2;
    const int* srcA = ei;
    const int* dstA = ei + E;

    char* ws = (char*)d_ws;
    size_t cur = 0;
    auto alloc = [&](size_t bytes) -> char* {
        char* p = ws + cur;
        cur += (bytes + 255) & ~(size_t)255;
        return p;
    };
    float*   h2     = (float*)alloc((size_t)N * 64 * 4);
    ushortT* hg1    = (ushortT*)alloc((size_t)N * 256 * 2);
    float*   a1s    = (float*)alloc((size_t)N * 4 * 4);
    float*   a1d    = (float*)alloc((size_t)N * 4 * 4);
    float*   out1   = (float*)alloc((size_t)N * 256 * 4);
    ushortT* hg2    = (ushortT*)alloc((size_t)N * 32 * 2);
    float*   a2s    = (float*)alloc((size_t)N * 4);
    float*   a2d    = (float*)alloc((size_t)N * 4);
    int*     deg    = (int*)alloc((size_t)(N + 1) * 4);
    int*     offs   = (int*)alloc((size_t)(N + 1) * 4);
    int*     cursor = (int*)alloc((size_t)N * 4);
    int*     bsum   = (int*)alloc(1024);
    int*     csr    = (int*)alloc((size_t)E * 4);
    float*   colsum = (float*)alloc(1024);
    float*   colsq  = (float*)alloc(1024);
    float*   cscale = (float*)alloc(1024);
    float*   cshift = (float*)alloc(1024);

    // h1 [N,128] only live between k_lin1 and k_lin2 -> alias onto out1 ([N,256])
    float* h1 = out1;

    hipMemsetAsync(deg, 0, (size_t)(N + 1) * 4, stream);
    hipMemsetAsync(colsum, 0, 2048, stream);

    const int EB = (E + 255) / 256;
    const int NB = (N + 255) / 256;
    const int B64 = (N + 63) / 64;
    const int B32 = (N + 31) / 32;
    const int B4  = (N + 3) / 4;

    k_lin1<<<B64, 256, 0, stream>>>(x, t1w, t1b, h1, N);
    k_lin2<<<B64, 256, 0, stream>>>(h1, t2w, t2b, h2, N);
    k_g1feat<<<B32, 256, 0, stream>>>(h2, g1w, g1as, g1ad, hg1, a1s, a1d, N);
    k_hist<<<EB, 256, 0, stream>>>(dstA, deg, E);
    k_scan1<<<NB, 256, 0, stream>>>(deg, offs, bsum, N);
    k_scan2<<<1, 256, 0, stream>>>(bsum, NB);
    k_scan3<<<NB, 256, 0, stream>>>(offs, cursor, bsum, N, E);
    k_scatter<<<EB, 256, 0, stream>>>(srcA, dstA, cursor, csr, E);
    k_gat1_agg<<<B4, 256, 0, stream>>>(hg1, a1s, a1d, offs, csr, g1b, out1, N);
    k_colstat<<<256, 256, 0, stream>>>(out1, colsum, colsq, N);
    k_norm_params<<<1, 256, 0, stream>>>(colsum, colsq, gnw, gnb, gnms, cscale, cshift, N);
    k_g2feat<<<B64, 256, 0, stream>>>(out1, cscale, cshift, g2w, g2as, g2ad, hg2, a2s, a2d, N);
    k_gat2_agg<<<B4, 256, 0, stream>>>(hg2, a2s, a2d, offs, csr, g2b, (float*)d_out, N);
}

// Round 4
// 426.471 us; speedup vs baseline: 1.8051x; 1.0316x over previous
//
#include <hip/hip_runtime.h>

#define NSLOPE 0.2f
#define GEPS 1e-5f

typedef unsigned short ushortT;
typedef __attribute__((ext_vector_type(8))) unsigned short us8;

__device__ __forceinline__ float lrelu(float x) { return x >= 0.f ? x : NSLOPE * x; }
__device__ __forceinline__ ushortT f2bf(float f) {
    unsigned int u = __float_as_uint(f);
    return (ushortT)((u + 0x7fffu + ((u >> 16) & 1u)) >> 16);
}
__device__ __forceinline__ float bf2f(ushortT h) {
    return __uint_as_float((unsigned int)h << 16);
}

// =================== dense transforms: LDS-staged register-blocked GEMMs ===================

// G1: h1 = relu(x @ w1 + b1)   x:[N,256] w1:[256,128]  tile 64x128, K-chunk 64
__global__ __launch_bounds__(256) void k_lin1(const float* __restrict__ x,
    const float* __restrict__ w1, const float* __restrict__ b1,
    float* __restrict__ h1, int n)
{
    __shared__ float xs[64][68];
    __shared__ float ws[64][132];
    const int t = threadIdx.x;
    const int n0g = blockIdx.x * 64;
    const int nb = (t & 15) * 4, c0 = (t >> 4) * 8;
    float acc[4][8];
    #pragma unroll
    for (int a = 0; a < 4; ++a)
        #pragma unroll
        for (int b = 0; b < 8; ++b) acc[a][b] = 0.f;

    for (int kc = 0; kc < 4; ++kc) {
        __syncthreads();
        #pragma unroll
        for (int i = 0; i < 4; ++i) {
            const int idx = i * 256 + t;
            const int node = idx >> 4, kk = (idx & 15) * 4;
            int gn = n0g + node; if (gn >= n) gn = n - 1;
            const float4 v = *(const float4*)&x[(size_t)gn * 256 + kc * 64 + kk];
            xs[kk][node] = v.x; xs[kk + 1][node] = v.y; xs[kk + 2][node] = v.z; xs[kk + 3][node] = v.w;
        }
        #pragma unroll
        for (int i = 0; i < 8; ++i) {
            const int idx = i * 256 + t;
            const int kk = idx >> 5, cc = (idx & 31) * 4;
            *(float4*)&ws[kk][cc] = *(const float4*)&w1[(size_t)(kc * 64 + kk) * 128 + cc];
        }
        __syncthreads();
        #pragma unroll 4
        for (int kk = 0; kk < 64; ++kk) {
            const float4 xv = *(const float4*)&xs[kk][nb];
            const float4 wa = *(const float4*)&ws[kk][c0];
            const float4 wb = *(const float4*)&ws[kk][c0 + 4];
            const float xr[4] = {xv.x, xv.y, xv.z, xv.w};
            const float wr[8] = {wa.x, wa.y, wa.z, wa.w, wb.x, wb.y, wb.z, wb.w};
            #pragma unroll
            for (int a = 0; a < 4; ++a)
                #pragma unroll
                for (int b = 0; b < 8; ++b) acc[a][b] = fmaf(xr[a], wr[b], acc[a][b]);
        }
    }
    float bb[8];
    #pragma unroll
    for (int b = 0; b < 8; ++b) bb[b] = b1[c0 + b];
    #pragma unroll
    for (int a = 0; a < 4; ++a) {
        const int gn = n0g + nb + a;
        if (gn < n) {
            float4 o0, o1;
            o0.x = fmaxf(acc[a][0] + bb[0], 0.f); o0.y = fmaxf(acc[a][1] + bb[1], 0.f);
            o0.z = fmaxf(acc[a][2] + bb[2], 0.f); o0.w = fmaxf(acc[a][3] + bb[3], 0.f);
            o1.x = fmaxf(acc[a][4] + bb[4], 0.f); o1.y = fmaxf(acc[a][5] + bb[5], 0.f);
            o1.z = fmaxf(acc[a][6] + bb[6], 0.f); o1.w = fmaxf(acc[a][7] + bb[7], 0.f);
            *(float4*)&h1[(size_t)gn * 128 + c0] = o0;
            *(float4*)&h1[(size_t)gn * 128 + c0 + 4] = o1;
        }
    }
}

// G2: h2 = relu(h1 @ w2 + b2)  h1:[N,128] w2:[128,64]  tile 64x64
__global__ __launch_bounds__(256) void k_lin2(const float* __restrict__ h1,
    const float* __restrict__ w2, const float* __restrict__ b2,
    float* __restrict__ h2, int n)
{
    __shared__ float xs[64][68];
    __shared__ float ws[64][68];
    const int t = threadIdx.x;
    const int n0g = blockIdx.x * 64;
    const int nb = (t & 15) * 4, c0 = (t >> 4) * 4;
    float acc[4][4];
    #pragma unroll
    for (int a = 0; a < 4; ++a)
        #pragma unroll
        for (int b = 0; b < 4; ++b) acc[a][b] = 0.f;

    for (int kc = 0; kc < 2; ++kc) {
        __syncthreads();
        #pragma unroll
        for (int i = 0; i < 4; ++i) {
            const int idx = i * 256 + t;
            const int node = idx >> 4, kk = (idx & 15) * 4;
            int gn = n0g + node; if (gn >= n) gn = n - 1;
            const float4 v = *(const float4*)&h1[(size_t)gn * 128 + kc * 64 + kk];
            xs[kk][node] = v.x; xs[kk + 1][node] = v.y; xs[kk + 2][node] = v.z; xs[kk + 3][node] = v.w;
        }
        #pragma unroll
        for (int i = 0; i < 4; ++i) {
            const int idx = i * 256 + t;
            const int kk = idx >> 4, cc = (idx & 15) * 4;
            *(float4*)&ws[kk][cc] = *(const float4*)&w2[(size_t)(kc * 64 + kk) * 64 + cc];
        }
        __syncthreads();
        #pragma unroll 4
        for (int kk = 0; kk < 64; ++kk) {
            const float4 xv = *(const float4*)&xs[kk][nb];
            const float4 wa = *(const float4*)&ws[kk][c0];
            const float xr[4] = {xv.x, xv.y, xv.z, xv.w};
            const float wr[4] = {wa.x, wa.y, wa.z, wa.w};
            #pragma unroll
            for (int a = 0; a < 4; ++a)
                #pragma unroll
                for (int b = 0; b < 4; ++b) acc[a][b] = fmaf(xr[a], wr[b], acc[a][b]);
        }
    }
    float bb[4];
    #pragma unroll
    for (int b = 0; b < 4; ++b) bb[b] = b2[c0 + b];
    #pragma unroll
    for (int a = 0; a < 4; ++a) {
        const int gn = n0g + nb + a;
        if (gn < n) {
            float4 o;
            o.x = fmaxf(acc[a][0] + bb[0], 0.f); o.y = fmaxf(acc[a][1] + bb[1], 0.f);
            o.z = fmaxf(acc[a][2] + bb[2], 0.f); o.w = fmaxf(acc[a][3] + bb[3], 0.f);
            *(float4*)&h2[(size_t)gn * 64 + c0] = o;
        }
    }
}

// G3: hg1(bf16) = h2 @ g1w ; a1s/a1d per (node,head)
__global__ __launch_bounds__(256) void k_g1feat(const float* __restrict__ h2,
    const float* __restrict__ w, const float* __restrict__ attS, const float* __restrict__ attD,
    ushortT* __restrict__ hg1, float* __restrict__ a1s, float* __restrict__ a1d, int n)
{
    __shared__ float xs[32][36];
    __shared__ float ws[32][260];
    __shared__ float as[32][4], ad[32][4];
    const int t = threadIdx.x;
    const int n0g = blockIdx.x * 32;
    const int nb = (t & 7) * 4, c0 = (t >> 3) * 8;
    if (t < 128) { ((float*)as)[t] = 0.f; ((float*)ad)[t] = 0.f; }
    float acc[4][8];
    #pragma unroll
    for (int a = 0; a < 4; ++a)
        #pragma unroll
        for (int b = 0; b < 8; ++b) acc[a][b] = 0.f;

    for (int kc = 0; kc < 2; ++kc) {
        __syncthreads();
        {
            const int node = t >> 3, kk = (t & 7) * 4;
            int gn = n0g + node; if (gn >= n) gn = n - 1;
            const float4 v = *(const float4*)&h2[(size_t)gn * 64 + kc * 32 + kk];
            xs[kk][node] = v.x; xs[kk + 1][node] = v.y; xs[kk + 2][node] = v.z; xs[kk + 3][node] = v.w;
        }
        #pragma unroll
        for (int i = 0; i < 8; ++i) {
            const int idx = i * 256 + t;
            const int kk = idx >> 6, cc = (idx & 63) * 4;
            *(float4*)&ws[kk][cc] = *(const float4*)&w[(size_t)(kc * 32 + kk) * 256 + cc];
        }
        __syncthreads();
        #pragma unroll 4
        for (int kk = 0; kk < 32; ++kk) {
            const float4 xv = *(const float4*)&xs[kk][nb];
            const float4 wa = *(const float4*)&ws[kk][c0];
            const float4 wb = *(const float4*)&ws[kk][c0 + 4];
            const float xr[4] = {xv.x, xv.y, xv.z, xv.w};
            const float wr[8] = {wa.x, wa.y, wa.z, wa.w, wb.x, wb.y, wb.z, wb.w};
            #pragma unroll
            for (int a = 0; a < 4; ++a)
                #pragma unroll
                for (int b = 0; b < 8; ++b) acc[a][b] = fmaf(xr[a], wr[b], acc[a][b]);
        }
    }
    const int head = c0 >> 6;
    float asr[8], adr[8];
    #pragma unroll
    for (int b = 0; b < 8; ++b) { asr[b] = attS[c0 + b]; adr[b] = attD[c0 + b]; }
    #pragma unroll
    for (int a = 0; a < 4; ++a) {
        const int gn = n0g + nb + a;
        float ps = 0.f, pd = 0.f;
        #pragma unroll
        for (int b = 0; b < 8; ++b) { ps = fmaf(acc[a][b], asr[b], ps); pd = fmaf(acc[a][b], adr[b], pd); }
        atomicAdd(&as[nb + a][head], ps);
        atomicAdd(&ad[nb + a][head], pd);
        if (gn < n) {
            us8 o;
            #pragma unroll
            for (int b = 0; b < 8; ++b) o[b] = f2bf(acc[a][b]);
            *(us8*)&hg1[(size_t)gn * 256 + c0] = o;
        }
    }
    __syncthreads();
    if (t < 128) {
        const int node = t >> 2, h = t & 3;
        const int gn = n0g + node;
        if (gn < n) { a1s[gn * 4 + h] = as[node][h]; a1d[gn * 4 + h] = ad[node][h]; }
    }
}

// G4: hg2(bf16) = elu(norm(out1)) @ g2w ; a2s/a2d
__global__ __launch_bounds__(256) void k_g2feat(const float* __restrict__ out1,
    const float* __restrict__ cscale, const float* __restrict__ cshift,
    const float* __restrict__ w, const float* __restrict__ attS, const float* __restrict__ attD,
    ushortT* __restrict__ hg2, float* __restrict__ a2s, float* __restrict__ a2d, int n)
{
    __shared__ float xs[64][68];
    __shared__ float ws[64][36];
    __shared__ float as[64], ad[64];
    const int t = threadIdx.x;
    const int n0g = blockIdx.x * 64;
    const int nb = (t & 15) * 4, c0 = (t >> 4) * 2;
    if (t < 64) { as[t] = 0.f; ad[t] = 0.f; }
    float acc[4][2];
    #pragma unroll
    for (int a = 0; a < 4; ++a) { acc[a][0] = 0.f; acc[a][1] = 0.f; }

    for (int kc = 0; kc < 4; ++kc) {
        __syncthreads();
        #pragma unroll
        for (int i = 0; i < 4; ++i) {
            const int idx = i * 256 + t;
            const int node = idx >> 4, kk = (idx & 15) * 4;
            int gn = n0g + node; if (gn >= n) gn = n - 1;
            float4 v = *(const float4*)&out1[(size_t)gn * 256 + kc * 64 + kk];
            const float4 sc = *(const float4*)&cscale[kc * 64 + kk];
            const float4 sh = *(const float4*)&cshift[kc * 64 + kk];
            v.x = v.x * sc.x + sh.x; v.y = v.y * sc.y + sh.y;
            v.z = v.z * sc.z + sh.z; v.w = v.w * sc.w + sh.w;
            v.x = v.x > 0.f ? v.x : __expf(v.x) - 1.f;
            v.y = v.y > 0.f ? v.y : __expf(v.y) - 1.f;
            v.z = v.z > 0.f ? v.z : __expf(v.z) - 1.f;
            v.w = v.w > 0.f ? v.w : __expf(v.w) - 1.f;
            xs[kk][node] = v.x; xs[kk + 1][node] = v.y; xs[kk + 2][node] = v.z; xs[kk + 3][node] = v.w;
        }
        #pragma unroll
        for (int i = 0; i < 2; ++i) {
            const int idx = i * 256 + t;
            const int kk = idx >> 3, cc = (idx & 7) * 4;
            *(float4*)&ws[kk][cc] = *(const float4*)&w[(size_t)(kc * 64 + kk) * 32 + cc];
        }
        __syncthreads();
        #pragma unroll 8
        for (int kk = 0; kk < 64; ++kk) {
            const float4 xv = *(const float4*)&xs[kk][nb];
            const float2 wa = *(const float2*)&ws[kk][c0];
            const float xr[4] = {xv.x, xv.y, xv.z, xv.w};
            #pragma unroll
            for (int a = 0; a < 4; ++a) {
                acc[a][0] = fmaf(xr[a], wa.x, acc[a][0]);
                acc[a][1] = fmaf(xr[a], wa.y, acc[a][1]);
            }
        }
    }
    const float s0 = attS[c0], s1 = attS[c0 + 1], d0 = attD[c0], d1 = attD[c0 + 1];
    #pragma unroll
    for (int a = 0; a < 4; ++a) {
        const int gn = n0g + nb + a;
        atomicAdd(&as[nb + a], acc[a][0] * s0 + acc[a][1] * s1);
        atomicAdd(&ad[nb + a], acc[a][0] * d0 + acc[a][1] * d1);
        if (gn < n) {
            ushort2 o = {f2bf(acc[a][0]), f2bf(acc[a][1])};
            *(ushort2*)&hg2[(size_t)gn * 32 + c0] = o;
        }
    }
    __syncthreads();
    if (t < 64) {
        const int gn = n0g + t;
        if (gn < n) { a2s[gn] = as[t]; a2d[gn] = ad[t]; }
    }
}

// ---------------- CSR build ----------------
__global__ void k_hist(const int* __restrict__ dst, int* __restrict__ deg, int e) {
    int i = blockIdx.x * 256 + threadIdx.x;
    if (i < e) atomicAdd(&deg[dst[i]], 1);
}

__global__ __launch_bounds__(256) void k_scan1(const int* __restrict__ deg, int* __restrict__ offs,
                                               int* __restrict__ bsum, int n)
{
    __shared__ int sm[256];
    const int t = threadIdx.x;
    const int i = blockIdx.x * 256 + t;
    const int v = (i < n) ? deg[i] : 0;
    sm[t] = v;
    __syncthreads();
    for (int off = 1; off < 256; off <<= 1) {
        int add = (t >= off) ? sm[t - off] : 0;
        __syncthreads();
        sm[t] += add;
        __syncthreads();
    }
    if (i < n) offs[i] = sm[t] - v;
    if (t == 255) bsum[blockIdx.x] = sm[255];
}

__global__ __launch_bounds__(256) void k_scan2(int* __restrict__ bsum, int nb) {
    __shared__ int sm[256];
    const int t = threadIdx.x;
    const int v = (t < nb) ? bsum[t] : 0;
    sm[t] = v;
    __syncthreads();
    for (int off = 1; off < 256; off <<= 1) {
        int add = (t >= off) ? sm[t - off] : 0;
        __syncthreads();
        sm[t] += add;
        __syncthreads();
    }
    if (t < nb) bsum[t] = sm[t] - v;
}

__global__ void k_scan3(int* __restrict__ offs, int* __restrict__ cursor,
                        const int* __restrict__ bsum, int n, int e) {
    int i = blockIdx.x * 256 + threadIdx.x;
    if (i < n) {
        int o = offs[i] + bsum[i >> 8];
        offs[i] = o;
        cursor[i] = o;
    }
    if (i == 0) offs[n] = e;
}

__global__ void k_scatter(const int* __restrict__ src, const int* __restrict__ dst,
                          int* __restrict__ cursor, int* __restrict__ csr, int e) {
    int i = blockIdx.x * 256 + threadIdx.x;
    if (i < e) {
        int p = atomicAdd(&cursor[dst[i]], 1);
        csr[p] = src[i];
    }
}

// ---------------- GAT1 alpha precompute: 16-lane group per node ----------------
__global__ __launch_bounds__(256) void k_alpha1(
    const float* __restrict__ a1s, const float* __restrict__ a1d,
    const int* __restrict__ offs, const int* __restrict__ csr,
    float* __restrict__ alphaE, int n)
{
    const int l = threadIdx.x & 15;
    const int d = blockIdx.x * 16 + (threadIdx.x >> 4);
    if (d >= n) return;
    const int start = offs[d], end = offs[d + 1];
    const float4* __restrict__ a1s4 = (const float4*)a1s;
    const float4 adv = ((const float4*)a1d)[d];
    const float ad0 = adv.x, ad1 = adv.y, ad2 = adv.z, ad3 = adv.w;

    float m0 = -1e30f, m1 = -1e30f, m2 = -1e30f, m3 = -1e30f;
    float s0 = 0.f, s1 = 0.f, s2 = 0.f, s3 = 0.f;
    for (int e = start + l; e < end; e += 16) {
        const float4 av = a1s4[csr[e]];
        const float l0 = lrelu(av.x + ad0), l1 = lrelu(av.y + ad1);
        const float l2 = lrelu(av.z + ad2), l3 = lrelu(av.w + ad3);
        float nm;
        nm = fmaxf(m0, l0); s0 = s0 * __expf(m0 - nm) + __expf(l0 - nm); m0 = nm;
        nm = fmaxf(m1, l1); s1 = s1 * __expf(m1 - nm) + __expf(l1 - nm); m1 = nm;
        nm = fmaxf(m2, l2); s2 = s2 * __expf(m2 - nm) + __expf(l2 - nm); m2 = nm;
        nm = fmaxf(m3, l3); s3 = s3 * __expf(m3 - nm) + __expf(l3 - nm); m3 = nm;
    }
    for (int off = 1; off < 16; off <<= 1) {
        float om, os, nm;
        om = __shfl_xor(m0, off, 16); os = __shfl_xor(s0, off, 16);
        nm = fmaxf(m0, om); s0 = s0 * __expf(m0 - nm) + os * __expf(om - nm); m0 = nm;
        om = __shfl_xor(m1, off, 16); os = __shfl_xor(s1, off, 16);
        nm = fmaxf(m1, om); s1 = s1 * __expf(m1 - nm) + os * __expf(om - nm); m1 = nm;
        om = __shfl_xor(m2, off, 16); os = __shfl_xor(s2, off, 16);
        nm = fmaxf(m2, om); s2 = s2 * __expf(m2 - nm) + os * __expf(om - nm); m2 = nm;
        om = __shfl_xor(m3, off, 16); os = __shfl_xor(s3, off, 16);
        nm = fmaxf(m3, om); s3 = s3 * __expf(m3 - nm) + os * __expf(om - nm); m3 = nm;
    }
    const float i0 = 1.f / (s0 + 1e-16f), i1 = 1.f / (s1 + 1e-16f);
    const float i2 = 1.f / (s2 + 1e-16f), i3 = 1.f / (s3 + 1e-16f);
    for (int e = start + l; e < end; e += 16) {
        const float4 av = a1s4[csr[e]];
        float4 o;
        o.x = __expf(lrelu(av.x + ad0) - m0) * i0;
        o.y = __expf(lrelu(av.y + ad1) - m1) * i1;
        o.z = __expf(lrelu(av.z + ad2) - m2) * i2;
        o.w = __expf(lrelu(av.w + ad3) - m3) * i3;
        *(float4*)&alphaE[(size_t)e * 4] = o;
    }
}

// ---------------- GAT1 PV gather: wave per node, no shuffles ----------------
__global__ __launch_bounds__(256) void k_pv1(
    const ushortT* __restrict__ hg1, const float* __restrict__ alphaE,
    const int* __restrict__ offs, const int* __restrict__ csr,
    const float* __restrict__ bias, float* __restrict__ out1, int n)
{
    const int lane = threadIdx.x & 63;
    const int d = blockIdx.x * 4 + (threadIdx.x >> 6);
    if (d >= n) return;
    const int start = offs[d], end = offs[d + 1];
    const int c = lane * 4;
    const int head = lane >> 4;
    float acc0 = 0.f, acc1 = 0.f, acc2 = 0.f, acc3 = 0.f;
    #pragma unroll 4
    for (int e = start; e < end; ++e) {
        const int si = csr[e];
        const float al = alphaE[(size_t)e * 4 + head];
        const ushort4 hv = *(const ushort4*)&hg1[(size_t)si * 256 + c];
        acc0 = fmaf(al, bf2f(hv.x), acc0);
        acc1 = fmaf(al, bf2f(hv.y), acc1);
        acc2 = fmaf(al, bf2f(hv.z), acc2);
        acc3 = fmaf(al, bf2f(hv.w), acc3);
    }
    const float4 bv = *(const float4*)&bias[c];
    float4 o = {acc0 + bv.x, acc1 + bv.y, acc2 + bv.z, acc3 + bv.w};
    *(float4*)&out1[(size_t)d * 256 + c] = o;
}

// ---------------- GraphNorm ----------------
__global__ __launch_bounds__(256) void k_colstat(const float* __restrict__ out1,
    float* __restrict__ colsum, float* __restrict__ colsq, int n)
{
    const int t = threadIdx.x;
    float s = 0.f, q = 0.f;
    for (int r = blockIdx.x; r < n; r += gridDim.x) {
        float v = out1[(size_t)r * 256 + t];
        s += v;
        q += v * v;
    }
    atomicAdd(&colsum[t], s);
    atomicAdd(&colsq[t], q);
}

__global__ void k_norm_params(const float* __restrict__ colsum, const float* __restrict__ colsq,
    const float* __restrict__ gw, const float* __restrict__ gb, const float* __restrict__ gms,
    float* __restrict__ scale, float* __restrict__ shift, int n)
{
    const int t = threadIdx.x;
    const float invn = 1.f / (float)n;
    const float mean = colsum[t] * invn;
    const float msq = colsq[t] * invn;
    const float ms = gms[t];
    const float var = msq - 2.f * ms * mean * mean + ms * ms * mean * mean;
    const float sc = gw[t] * rsqrtf(var + GEPS);
    scale[t] = sc;
    shift[t] = gb[t] - mean * ms * sc;
}

// ---------------- GAT2 alpha precompute: 16-lane group per node (1 head) ----------------
__global__ __launch_bounds__(256) void k_alpha2(
    const float* __restrict__ a2s, const float* __restrict__ a2d,
    const int* __restrict__ offs, const int* __restrict__ csr,
    float* __restrict__ alphaE2, int n)
{
    const int l = threadIdx.x & 15;
    const int d = blockIdx.x * 16 + (threadIdx.x >> 4);
    if (d >= n) return;
    const int start = offs[d], end = offs[d + 1];
    const float adv = a2d[d];
    float m = -1e30f, s = 0.f;
    for (int e = start + l; e < end; e += 16) {
        const float lv = lrelu(a2s[csr[e]] + adv);
        const float nm = fmaxf(m, lv);
        s = s * __expf(m - nm) + __expf(lv - nm);
        m = nm;
    }
    for (int off = 1; off < 16; off <<= 1) {
        const float om = __shfl_xor(m, off, 16), os = __shfl_xor(s, off, 16);
        const float nm = fmaxf(m, om);
        s = s * __expf(m - nm) + os * __expf(om - nm);
        m = nm;
    }
    const float inv = 1.f / (s + 1e-16f);
    for (int e = start + l; e < end; e += 16)
        alphaE2[e] = __expf(lrelu(a2s[csr[e]] + adv) - m) * inv;
}

// ---------------- GAT2 PV + bias + log_softmax: 32-lane group per node ----------------
__global__ __launch_bounds__(256) void k_pv2(
    const ushortT* __restrict__ hg2, const float* __restrict__ alphaE2,
    const int* __restrict__ offs, const int* __restrict__ csr,
    const float* __restrict__ bias, float* __restrict__ out, int n)
{
    const int l = threadIdx.x & 31;
    const int d = blockIdx.x * 8 + (threadIdx.x >> 5);
    if (d >= n) return;
    const int start = offs[d], end = offs[d + 1];
    float acc = 0.f;
    #pragma unroll 4
    for (int e = start; e < end; ++e) {
        const int si = csr[e];
        const float al = alphaE2[e];
        acc = fmaf(al, bf2f(hg2[(size_t)si * 32 + l]), acc);
    }
    const float v = acc + bias[l];
    float mx = v;
    for (int off = 16; off; off >>= 1) mx = fmaxf(mx, __shfl_xor(mx, off, 32));
    float se = __expf(v - mx);
    for (int off = 16; off; off >>= 1) se += __shfl_xor(se, off, 32);
    out[(size_t)d * 32 + l] = v - mx - __logf(se);
}

// ---------------- launcher ----------------
extern "C" void kernel_launch(void* const* d_in, const int* in_sizes, int n_in,
                              void* d_out, int out_size, void* d_ws, size_t ws_size,
                              hipStream_t stream)
{
    const float* x    = (const float*)d_in[0];
    const int*   ei   = (const int*)d_in[1];
    const float* t1w  = (const float*)d_in[2];
    const float* t1b  = (const float*)d_in[3];
    const float* t2w  = (const float*)d_in[4];
    const float* t2b  = (const float*)d_in[5];
    const float* g1w  = (const float*)d_in[6];
    const float* g1as = (const float*)d_in[7];
    const float* g1ad = (const float*)d_in[8];
    const float* g1b  = (const float*)d_in[9];
    const float* gnw  = (const float*)d_in[10];
    const float* gnb  = (const float*)d_in[11];
    const float* gnms = (const float*)d_in[12];
    const float* g2w  = (const float*)d_in[13];
    const float* g2as = (const float*)d_in[14];
    const float* g2ad = (const float*)d_in[15];
    const float* g2b  = (const float*)d_in[16];

    const int N = in_sizes[0] / 256;
    const int E = in_sizes[1] / 2;
    const int* srcA = ei;
    const int* dstA = ei + E;

    char* ws = (char*)d_ws;
    size_t cur = 0;
    auto alloc = [&](size_t bytes) -> char* {
        char* p = ws + cur;
        cur += (bytes + 255) & ~(size_t)255;
        return p;
    };
    float*   h2      = (float*)alloc((size_t)N * 64 * 4);
    ushortT* hg1     = (ushortT*)alloc((size_t)N * 256 * 2);
    float*   a1s     = (float*)alloc((size_t)N * 4 * 4);
    float*   a1d     = (float*)alloc((size_t)N * 4 * 4);
    float*   out1    = (float*)alloc((size_t)N * 256 * 4);
    ushortT* hg2     = (ushortT*)alloc((size_t)N * 32 * 2);
    float*   a2s     = (float*)alloc((size_t)N * 4);
    float*   a2d     = (float*)alloc((size_t)N * 4);
    int*     deg     = (int*)alloc((size_t)(N + 1) * 4);
    int*     offs    = (int*)alloc((size_t)(N + 1) * 4);
    int*     cursor  = (int*)alloc((size_t)N * 4);
    int*     bsum    = (int*)alloc(1024);
    int*     csr     = (int*)alloc((size_t)E * 4);
    float*   alphaE  = (float*)alloc((size_t)E * 4 * 4);
    float*   alphaE2 = (float*)alloc((size_t)E * 4);
    float*   colsum  = (float*)alloc(1024);
    float*   colsq   = (float*)alloc(1024);
    float*   cscale  = (float*)alloc(1024);
    float*   cshift  = (float*)alloc(1024);

    // h1 [N,128] only live between k_lin1 and k_lin2 -> alias onto out1 ([N,256])
    float* h1 = out1;

    hipMemsetAsync(deg, 0, (size_t)(N + 1) * 4, stream);
    hipMemsetAsync(colsum, 0, 2048, stream);

    const int EB  = (E + 255) / 256;
    const int NB  = (N + 255) / 256;
    const int B64 = (N + 63) / 64;
    const int B32 = (N + 31) / 32;
    const int B16 = (N + 15) / 16;
    const int B8  = (N + 7) / 8;
    const int B4  = (N + 3) / 4;

    k_lin1<<<B64, 256, 0, stream>>>(x, t1w, t1b, h1, N);
    k_lin2<<<B64, 256, 0, stream>>>(h1, t2w, t2b, h2, N);
    k_g1feat<<<B32, 256, 0, stream>>>(h2, g1w, g1as, g1ad, hg1, a1s, a1d, N);
    k_hist<<<EB, 256, 0, stream>>>(dstA, deg, E);
    k_scan1<<<NB, 256, 0, stream>>>(deg, offs, bsum, N);
    k_scan2<<<1, 256, 0, stream>>>(bsum, NB);
    k_scan3<<<NB, 256, 0, stream>>>(offs, cursor, bsum, N, E);
    k_scatter<<<EB, 256, 0, stream>>>(srcA, dstA, cursor, csr, E);
    k_alpha1<<<B16, 256, 0, stream>>>(a1s, a1d, offs, csr, alphaE, N);
    k_pv1<<<B4, 256, 0, stream>>>(hg1, alphaE, offs, csr, g1b, out1, N);
    k_colstat<<<256, 256, 0, stream>>>(out1, colsum, colsq, N);
    k_norm_params<<<1, 256, 0, stream>>>(colsum, colsq, gnw, gnb, gnms, cscale, cshift, N);
    k_g2feat<<<B64, 256, 0, stream>>>(out1, cscale, cshift, g2w, g2as, g2ad, hg2, a2s, a2d, N);
    k_alpha2<<<B16, 256, 0, stream>>>(a2s, a2d, offs, csr, alphaE2, N);
    k_pv2<<<B8, 256, 0, stream>>>(hg2, alphaE2, offs, csr, g2b, (float*)d_out, N);
}

// Round 5
// 324.720 us; speedup vs baseline: 2.3707x; 1.3134x over previous
//
#include <hip/hip_runtime.h>

#define NSLOPE 0.2f
#define GEPS 1e-5f

typedef unsigned short ushortT;
typedef __attribute__((ext_vector_type(8))) unsigned short us8;
typedef __attribute__((ext_vector_type(8))) __bf16 bf16x8;
typedef __attribute__((ext_vector_type(4))) float f32x4;

__device__ __forceinline__ float lrelu(float x) { return x >= 0.f ? x : NSLOPE * x; }
__device__ __forceinline__ ushortT f2bf(float f) {
    unsigned int u = __float_as_uint(f);
    return (ushortT)((u + 0x7fffu + ((u >> 16) & 1u)) >> 16);
}
__device__ __forceinline__ float bf2f(ushortT h) {
    return __uint_as_float((unsigned int)h << 16);
}

// ---------------- weight prep: transpose + bf16 convert ----------------
__global__ __launch_bounds__(256) void k_prep(
    const float* __restrict__ w1, const float* __restrict__ w2,
    const float* __restrict__ g1w, const float* __restrict__ g2w,
    ushortT* __restrict__ w1t, ushortT* __restrict__ w2t,
    ushortT* __restrict__ g1t, ushortT* __restrict__ g2t)
{
    const int i = blockIdx.x * 256 + threadIdx.x;
    if (i < 128 * 256) { const int c = i >> 8, k = i & 255; w1t[i] = f2bf(w1[k * 128 + c]); }
    if (i < 64 * 128)  { const int c = i >> 7, k = i & 127; w2t[i] = f2bf(w2[k * 64 + c]); }
    if (i < 256 * 64)  { const int c = i >> 6, k = i & 63;  g1t[i] = f2bf(g1w[k * 256 + c]); }
    if (i < 32 * 256)  { const int c = i >> 8, k = i & 255; g2t[i] = f2bf(g2w[k * 32 + c]); }
}

// ---------------- MFMA GEMM 1: h1(bf16) = relu(x @ w1 + b1)  [N,256]x[256,128] ----------------
__global__ __launch_bounds__(256) void k_lin1(const float* __restrict__ x,
    const ushortT* __restrict__ w1t, const float* __restrict__ b1,
    ushortT* __restrict__ h1, int n)
{
    __shared__ us8 Ab[64 * 128 / 16];    // 64 rows x 64 bf16, swizzled
    __shared__ us8 Bb[128 * 128 / 16];   // 128 cols x 64 bf16
    char* A = (char*)Ab; char* B = (char*)Bb;
    const int t = threadIdx.x;
    const int w = t >> 6, l = t & 63;
    const int lo = l & 15, hi = l >> 4;
    const int n0 = blockIdx.x * 64;
    const int wm = (w >> 1) * 32, wn = (w & 1) * 64;
    f32x4 acc[2][4];
    #pragma unroll
    for (int mf = 0; mf < 2; ++mf)
        #pragma unroll
        for (int nf = 0; nf < 4; ++nf) acc[mf][nf] = (f32x4){0.f, 0.f, 0.f, 0.f};

    const int arow = t >> 2, ak0 = (t & 3) * 16;
    int agn = n0 + arow; if (agn >= n) agn = n - 1;
    const int asw = (arow & 7) << 4;

    for (int kc = 0; kc < 4; ++kc) {
        __syncthreads();
        {   // stage A (fp32 -> bf16)
            ushortT tmp[16];
            const float* xp = &x[(size_t)agn * 256 + kc * 64 + ak0];
            #pragma unroll
            for (int j = 0; j < 4; ++j) {
                const float4 v = *(const float4*)(xp + j * 4);
                tmp[j*4+0] = f2bf(v.x); tmp[j*4+1] = f2bf(v.y);
                tmp[j*4+2] = f2bf(v.z); tmp[j*4+3] = f2bf(v.w);
            }
            *(us8*)(A + arow * 128 + ((ak0 * 2) ^ asw)) = *(us8*)tmp;
            *(us8*)(A + arow * 128 + ((ak0 * 2 + 16) ^ asw)) = *(us8*)(tmp + 8);
        }
        #pragma unroll
        for (int i = 0; i < 4; ++i) {   // stage B
            const int idx = i * 256 + t, br = idx >> 3, bs = idx & 7;
            const us8 v = *(const us8*)&w1t[(size_t)br * 256 + kc * 64 + bs * 8];
            *(us8*)(B + br * 128 + ((bs * 16) ^ ((br & 7) << 4))) = v;
        }
        __syncthreads();
        #pragma unroll
        for (int ks = 0; ks < 2; ++ks) {
            const int koff = ks * 64 + hi * 16;
            bf16x8 af[2], bf[4];
            #pragma unroll
            for (int mf = 0; mf < 2; ++mf) {
                const int r = wm + mf * 16 + lo;
                af[mf] = *(const bf16x8*)(A + r * 128 + (koff ^ ((r & 7) << 4)));
            }
            #pragma unroll
            for (int nf = 0; nf < 4; ++nf) {
                const int r = wn + nf * 16 + lo;
                bf[nf] = *(const bf16x8*)(B + r * 128 + (koff ^ ((r & 7) << 4)));
            }
            #pragma unroll
            for (int mf = 0; mf < 2; ++mf)
                #pragma unroll
                for (int nf = 0; nf < 4; ++nf)
                    acc[mf][nf] = __builtin_amdgcn_mfma_f32_16x16x32_bf16(af[mf], bf[nf], acc[mf][nf], 0, 0, 0);
        }
    }
    #pragma unroll
    for (int nf = 0; nf < 4; ++nf) {
        const int col = wn + nf * 16 + lo;
        const float bb = b1[col];
        #pragma unroll
        for (int mf = 0; mf < 2; ++mf)
            #pragma unroll
            for (int j = 0; j < 4; ++j) {
                const int r = n0 + wm + mf * 16 + hi * 4 + j;
                if (r < n) h1[(size_t)r * 128 + col] = f2bf(fmaxf(acc[mf][nf][j] + bb, 0.f));
            }
    }
}

// ---------------- MFMA GEMM 2: h2(bf16) = relu(h1 @ w2 + b2)  [N,128]x[128,64] ----------------
__global__ __launch_bounds__(256) void k_lin2(const ushortT* __restrict__ h1,
    const ushortT* __restrict__ w2t, const float* __restrict__ b2,
    ushortT* __restrict__ h2, int n)
{
    __shared__ us8 Ab[64 * 128 / 16];
    __shared__ us8 Bb[64 * 128 / 16];
    char* A = (char*)Ab; char* B = (char*)Bb;
    const int t = threadIdx.x;
    const int w = t >> 6, l = t & 63;
    const int lo = l & 15, hi = l >> 4;
    const int n0 = blockIdx.x * 64;
    const int wm = (w >> 1) * 32, wn = (w & 1) * 32;
    f32x4 acc[2][2];
    #pragma unroll
    for (int mf = 0; mf < 2; ++mf)
        #pragma unroll
        for (int nf = 0; nf < 2; ++nf) acc[mf][nf] = (f32x4){0.f, 0.f, 0.f, 0.f};

    const int arow = t >> 2, ak0 = (t & 3) * 16;
    int agn = n0 + arow; if (agn >= n) agn = n - 1;
    const int asw = (arow & 7) << 4;

    for (int kc = 0; kc < 2; ++kc) {
        __syncthreads();
        {
            const us8 v0 = *(const us8*)&h1[(size_t)agn * 128 + kc * 64 + ak0];
            const us8 v1 = *(const us8*)&h1[(size_t)agn * 128 + kc * 64 + ak0 + 8];
            *(us8*)(A + arow * 128 + ((ak0 * 2) ^ asw)) = v0;
            *(us8*)(A + arow * 128 + ((ak0 * 2 + 16) ^ asw)) = v1;
        }
        #pragma unroll
        for (int i = 0; i < 2; ++i) {
            const int idx = i * 256 + t, br = idx >> 3, bs = idx & 7;
            const us8 v = *(const us8*)&w2t[(size_t)br * 128 + kc * 64 + bs * 8];
            *(us8*)(B + br * 128 + ((bs * 16) ^ ((br & 7) << 4))) = v;
        }
        __syncthreads();
        #pragma unroll
        for (int ks = 0; ks < 2; ++ks) {
            const int koff = ks * 64 + hi * 16;
            bf16x8 af[2], bf[2];
            #pragma unroll
            for (int mf = 0; mf < 2; ++mf) {
                const int r = wm + mf * 16 + lo;
                af[mf] = *(const bf16x8*)(A + r * 128 + (koff ^ ((r & 7) << 4)));
            }
            #pragma unroll
            for (int nf = 0; nf < 2; ++nf) {
                const int r = wn + nf * 16 + lo;
                bf[nf] = *(const bf16x8*)(B + r * 128 + (koff ^ ((r & 7) << 4)));
            }
            #pragma unroll
            for (int mf = 0; mf < 2; ++mf)
                #pragma unroll
                for (int nf = 0; nf < 2; ++nf)
                    acc[mf][nf] = __builtin_amdgcn_mfma_f32_16x16x32_bf16(af[mf], bf[nf], acc[mf][nf], 0, 0, 0);
        }
    }
    #pragma unroll
    for (int nf = 0; nf < 2; ++nf) {
        const int col = wn + nf * 16 + lo;
        const float bb = b2[col];
        #pragma unroll
        for (int mf = 0; mf < 2; ++mf)
            #pragma unroll
            for (int j = 0; j < 4; ++j) {
                const int r = n0 + wm + mf * 16 + hi * 4 + j;
                if (r < n) h2[(size_t)r * 64 + col] = f2bf(fmaxf(acc[mf][nf][j] + bb, 0.f));
            }
    }
}

// ---------------- MFMA GEMM 3: hg1(bf16) = h2 @ g1w ; a1s/a1d  [N,64]x[64,256] ----------------
__global__ __launch_bounds__(256) void k_g1feat(const ushortT* __restrict__ h2,
    const ushortT* __restrict__ g1t, const float* __restrict__ attS, const float* __restrict__ attD,
    ushortT* __restrict__ hg1, float* __restrict__ a1s, float* __restrict__ a1d, int n)
{
    __shared__ us8 Ab[64 * 128 / 16];
    __shared__ us8 Bb[256 * 128 / 16];
    char* A = (char*)Ab; char* B = (char*)Bb;
    const int t = threadIdx.x;
    const int w = t >> 6, l = t & 63;
    const int lo = l & 15, hi = l >> 4;
    const int n0 = blockIdx.x * 64;
    const int wm = (w >> 1) * 32, wn = (w & 1) * 128;
    f32x4 acc[2][8];
    #pragma unroll
    for (int mf = 0; mf < 2; ++mf)
        #pragma unroll
        for (int nf = 0; nf < 8; ++nf) acc[mf][nf] = (f32x4){0.f, 0.f, 0.f, 0.f};

    {   // stage A (h2 bf16, K=64 full)
        const int arow = t >> 2, ak0 = (t & 3) * 16;
        int agn = n0 + arow; if (agn >= n) agn = n - 1;
        const int asw = (arow & 7) << 4;
        const us8 v0 = *(const us8*)&h2[(size_t)agn * 64 + ak0];
        const us8 v1 = *(const us8*)&h2[(size_t)agn * 64 + ak0 + 8];
        *(us8*)(A + arow * 128 + ((ak0 * 2) ^ asw)) = v0;
        *(us8*)(A + arow * 128 + ((ak0 * 2 + 16) ^ asw)) = v1;
    }
    #pragma unroll
    for (int i = 0; i < 8; ++i) {
        const int idx = i * 256 + t, br = idx >> 3, bs = idx & 7;
        const us8 v = *(const us8*)&g1t[(size_t)br * 64 + bs * 8];
        *(us8*)(B + br * 128 + ((bs * 16) ^ ((br & 7) << 4))) = v;
    }
    __syncthreads();
    #pragma unroll
    for (int ks = 0; ks < 2; ++ks) {
        const int koff = ks * 64 + hi * 16;
        bf16x8 af[2];
        #pragma unroll
        for (int mf = 0; mf < 2; ++mf) {
            const int r = wm + mf * 16 + lo;
            af[mf] = *(const bf16x8*)(A + r * 128 + (koff ^ ((r & 7) << 4)));
        }
        #pragma unroll
        for (int nf = 0; nf < 8; ++nf) {
            const int r = wn + nf * 16 + lo;
            const bf16x8 bf = *(const bf16x8*)(B + r * 128 + (koff ^ ((r & 7) << 4)));
            #pragma unroll
            for (int mf = 0; mf < 2; ++mf)
                acc[mf][nf] = __builtin_amdgcn_mfma_f32_16x16x32_bf16(af[mf], bf, acc[mf][nf], 0, 0, 0);
        }
    }
    // epilogue: bf16 store + att dot-products
    float sS[8], sD[8];
    #pragma unroll
    for (int nf = 0; nf < 8; ++nf) {
        sS[nf] = attS[wn + nf * 16 + lo];
        sD[nf] = attD[wn + nf * 16 + lo];
    }
    const int hA = wn >> 6, hB = hA + 1;
    #pragma unroll
    for (int mf = 0; mf < 2; ++mf)
        #pragma unroll
        for (int j = 0; j < 4; ++j) {
            const int r = n0 + wm + mf * 16 + hi * 4 + j;
            float pSA = 0.f, pDA = 0.f, pSB = 0.f, pDB = 0.f;
            #pragma unroll
            for (int nf = 0; nf < 4; ++nf) {
                pSA = fmaf(acc[mf][nf][j], sS[nf], pSA);
                pDA = fmaf(acc[mf][nf][j], sD[nf], pDA);
                pSB = fmaf(acc[mf][nf + 4][j], sS[nf + 4], pSB);
                pDB = fmaf(acc[mf][nf + 4][j], sD[nf + 4], pDB);
            }
            #pragma unroll
            for (int off = 1; off < 16; off <<= 1) {
                pSA += __shfl_xor(pSA, off);
                pDA += __shfl_xor(pDA, off);
                pSB += __shfl_xor(pSB, off);
                pDB += __shfl_xor(pDB, off);
            }
            if (r < n) {
                if (lo == 0) {
                    a1s[r * 4 + hA] = pSA; a1s[r * 4 + hB] = pSB;
                    a1d[r * 4 + hA] = pDA; a1d[r * 4 + hB] = pDB;
                }
                #pragma unroll
                for (int nf = 0; nf < 8; ++nf)
                    hg1[(size_t)r * 256 + wn + nf * 16 + lo] = f2bf(acc[mf][nf][j]);
            }
        }
}

// ---------------- MFMA GEMM 4: hg2(bf16) = elu(norm(out1)) @ g2w ; a2s/a2d  [N,256]x[256,32] ----------------
__global__ __launch_bounds__(256) void k_g2feat(const float* __restrict__ out1,
    const float* __restrict__ cscale, const float* __restrict__ cshift,
    const ushortT* __restrict__ g2t, const float* __restrict__ attS, const float* __restrict__ attD,
    ushortT* __restrict__ hg2, float* __restrict__ a2s, float* __restrict__ a2d, int n)
{
    __shared__ us8 Ab[64 * 128 / 16];
    __shared__ us8 Bb[32 * 128 / 16];
    char* A = (char*)Ab; char* B = (char*)Bb;
    const int t = threadIdx.x;
    const int w = t >> 6, l = t & 63;
    const int lo = l & 15, hi = l >> 4;
    const int n0 = blockIdx.x * 64;
    const int wm = w * 16;
    f32x4 acc[2];
    acc[0] = (f32x4){0.f, 0.f, 0.f, 0.f};
    acc[1] = (f32x4){0.f, 0.f, 0.f, 0.f};

    const int arow = t >> 2, ak0 = (t & 3) * 16;
    int agn = n0 + arow; if (agn >= n) agn = n - 1;
    const int asw = (arow & 7) << 4;

    for (int kc = 0; kc < 4; ++kc) {
        __syncthreads();
        {   // stage A with norm + elu
            ushortT tmp[16];
            const float* xp = &out1[(size_t)agn * 256 + kc * 64 + ak0];
            #pragma unroll
            for (int j = 0; j < 4; ++j) {
                float4 v = *(const float4*)(xp + j * 4);
                const float4 sc = *(const float4*)&cscale[kc * 64 + ak0 + j * 4];
                const float4 sh = *(const float4*)&cshift[kc * 64 + ak0 + j * 4];
                v.x = v.x * sc.x + sh.x; v.y = v.y * sc.y + sh.y;
                v.z = v.z * sc.z + sh.z; v.w = v.w * sc.w + sh.w;
                v.x = v.x > 0.f ? v.x : __expf(v.x) - 1.f;
                v.y = v.y > 0.f ? v.y : __expf(v.y) - 1.f;
                v.z = v.z > 0.f ? v.z : __expf(v.z) - 1.f;
                v.w = v.w > 0.f ? v.w : __expf(v.w) - 1.f;
                tmp[j*4+0] = f2bf(v.x); tmp[j*4+1] = f2bf(v.y);
                tmp[j*4+2] = f2bf(v.z); tmp[j*4+3] = f2bf(v.w);
            }
            *(us8*)(A + arow * 128 + ((ak0 * 2) ^ asw)) = *(us8*)tmp;
            *(us8*)(A + arow * 128 + ((ak0 * 2 + 16) ^ asw)) = *(us8*)(tmp + 8);
        }
        {   // stage B: 32 rows x 8 segs = 256
            const int br = t >> 3, bs = t & 7;
            const us8 v = *(const us8*)&g2t[(size_t)br * 256 + kc * 64 + bs * 8];
            *(us8*)(B + br * 128 + ((bs * 16) ^ ((br & 7) << 4))) = v;
        }
        __syncthreads();
        #pragma unroll
        for (int ks = 0; ks < 2; ++ks) {
            const int koff = ks * 64 + hi * 16;
            const int ra = wm + lo;
            const bf16x8 af = *(const bf16x8*)(A + ra * 128 + (koff ^ ((ra & 7) << 4)));
            #pragma unroll
            for (int nf = 0; nf < 2; ++nf) {
                const int r = nf * 16 + lo;
                const bf16x8 bf = *(const bf16x8*)(B + r * 128 + (koff ^ ((r & 7) << 4)));
                acc[nf] = __builtin_amdgcn_mfma_f32_16x16x32_bf16(af, bf, acc[nf], 0, 0, 0);
            }
        }
    }
    float sS[2], sD[2];
    sS[0] = attS[lo]; sS[1] = attS[16 + lo];
    sD[0] = attD[lo]; sD[1] = attD[16 + lo];
    #pragma unroll
    for (int j = 0; j < 4; ++j) {
        const int r = n0 + wm + hi * 4 + j;
        float pS = fmaf(acc[0][j], sS[0], acc[1][j] * sS[1]);
        float pD = fmaf(acc[0][j], sD[0], acc[1][j] * sD[1]);
        #pragma unroll
        for (int off = 1; off < 16; off <<= 1) {
            pS += __shfl_xor(pS, off);
            pD += __shfl_xor(pD, off);
        }
        if (r < n) {
            if (lo == 0) { a2s[r] = pS; a2d[r] = pD; }
            hg2[(size_t)r * 32 + lo] = f2bf(acc[0][j]);
            hg2[(size_t)r * 32 + 16 + lo] = f2bf(acc[1][j]);
        }
    }
}

// ---------------- CSR build ----------------
__global__ void k_hist(const int* __restrict__ dst, int* __restrict__ deg, int e) {
    int i = blockIdx.x * 256 + threadIdx.x;
    if (i < e) atomicAdd(&deg[dst[i]], 1);
}

__global__ __launch_bounds__(256) void k_scan1(const int* __restrict__ deg, int* __restrict__ offs,
                                               int* __restrict__ bsum, int n)
{
    __shared__ int sm[256];
    const int t = threadIdx.x;
    const int i = blockIdx.x * 256 + t;
    const int v = (i < n) ? deg[i] : 0;
    sm[t] = v;
    __syncthreads();
    for (int off = 1; off < 256; off <<= 1) {
        int add = (t >= off) ? sm[t - off] : 0;
        __syncthreads();
        sm[t] += add;
        __syncthreads();
    }
    if (i < n) offs[i] = sm[t] - v;
    if (t == 255) bsum[blockIdx.x] = sm[255];
}

__global__ __launch_bounds__(256) void k_scan2(int* __restrict__ bsum, int nb) {
    __shared__ int sm[256];
    const int t = threadIdx.x;
    const int v = (t < nb) ? bsum[t] : 0;
    sm[t] = v;
    __syncthreads();
    for (int off = 1; off < 256; off <<= 1) {
        int add = (t >= off) ? sm[t - off] : 0;
        __syncthreads();
        sm[t] += add;
        __syncthreads();
    }
    if (t < nb) bsum[t] = sm[t] - v;
}

__global__ void k_scan3(int* __restrict__ offs, int* __restrict__ cursor,
                        const int* __restrict__ bsum, int n, int e) {
    int i = blockIdx.x * 256 + threadIdx.x;
    if (i < n) {
        int o = offs[i] + bsum[i >> 8];
        offs[i] = o;
        cursor[i] = o;
    }
    if (i == 0) offs[n] = e;
}

__global__ void k_scatter(const int* __restrict__ src, const int* __restrict__ dst,
                          int* __restrict__ cursor, int* __restrict__ csr, int e) {
    int i = blockIdx.x * 256 + threadIdx.x;
    if (i < e) {
        int p = atomicAdd(&cursor[dst[i]], 1);
        csr[p] = src[i];
    }
}

// ---------------- GAT1 alpha precompute: 16-lane group per node ----------------
__global__ __launch_bounds__(256) void k_alpha1(
    const float* __restrict__ a1s, const float* __restrict__ a1d,
    const int* __restrict__ offs, const int* __restrict__ csr,
    float* __restrict__ alphaE, int n)
{
    const int l = threadIdx.x & 15;
    const int d = blockIdx.x * 16 + (threadIdx.x >> 4);
    if (d >= n) return;
    const int start = offs[d], end = offs[d + 1];
    const float4* __restrict__ a1s4 = (const float4*)a1s;
    const float4 adv = ((const float4*)a1d)[d];
    const float ad0 = adv.x, ad1 = adv.y, ad2 = adv.z, ad3 = adv.w;

    float m0 = -1e30f, m1 = -1e30f, m2 = -1e30f, m3 = -1e30f;
    float s0 = 0.f, s1 = 0.f, s2 = 0.f, s3 = 0.f;
    for (int e = start + l; e < end; e += 16) {
        const float4 av = a1s4[csr[e]];
        const float l0 = lrelu(av.x + ad0), l1 = lrelu(av.y + ad1);
        const float l2 = lrelu(av.z + ad2), l3 = lrelu(av.w + ad3);
        float nm;
        nm = fmaxf(m0, l0); s0 = s0 * __expf(m0 - nm) + __expf(l0 - nm); m0 = nm;
        nm = fmaxf(m1, l1); s1 = s1 * __expf(m1 - nm) + __expf(l1 - nm); m1 = nm;
        nm = fmaxf(m2, l2); s2 = s2 * __expf(m2 - nm) + __expf(l2 - nm); m2 = nm;
        nm = fmaxf(m3, l3); s3 = s3 * __expf(m3 - nm) + __expf(l3 - nm); m3 = nm;
    }
    for (int off = 1; off < 16; off <<= 1) {
        float om, os, nm;
        om = __shfl_xor(m0, off, 16); os = __shfl_xor(s0, off, 16);
        nm = fmaxf(m0, om); s0 = s0 * __expf(m0 - nm) + os * __expf(om - nm); m0 = nm;
        om = __shfl_xor(m1, off, 16); os = __shfl_xor(s1, off, 16);
        nm = fmaxf(m1, om); s1 = s1 * __expf(m1 - nm) + os * __expf(om - nm); m1 = nm;
        om = __shfl_xor(m2, off, 16); os = __shfl_xor(s2, off, 16);
        nm = fmaxf(m2, om); s2 = s2 * __expf(m2 - nm) + os * __expf(om - nm); m2 = nm;
        om = __shfl_xor(m3, off, 16); os = __shfl_xor(s3, off, 16);
        nm = fmaxf(m3, om); s3 = s3 * __expf(m3 - nm) + os * __expf(om - nm); m3 = nm;
    }
    const float i0 = 1.f / (s0 + 1e-16f), i1 = 1.f / (s1 + 1e-16f);
    const float i2 = 1.f / (s2 + 1e-16f), i3 = 1.f / (s3 + 1e-16f);
    for (int e = start + l; e < end; e += 16) {
        const float4 av = a1s4[csr[e]];
        float4 o;
        o.x = __expf(lrelu(av.x + ad0) - m0) * i0;
        o.y = __expf(lrelu(av.y + ad1) - m1) * i1;
        o.z = __expf(lrelu(av.z + ad2) - m2) * i2;
        o.w = __expf(lrelu(av.w + ad3) - m3) * i3;
        *(float4*)&alphaE[(size_t)e * 4] = o;
    }
}

// ---------------- GAT1 PV gather: wave per node, no shuffles ----------------
__global__ __launch_bounds__(256) void k_pv1(
    const ushortT* __restrict__ hg1, const float* __restrict__ alphaE,
    const int* __restrict__ offs, const int* __restrict__ csr,
    const float* __restrict__ bias, float* __restrict__ out1, int n)
{
    const int lane = threadIdx.x & 63;
    const int d = blockIdx.x * 4 + (threadIdx.x >> 6);
    if (d >= n) return;
    const int start = offs[d], end = offs[d + 1];
    const int c = lane * 4;
    const int head = lane >> 4;
    float acc0 = 0.f, acc1 = 0.f, acc2 = 0.f, acc3 = 0.f;
    #pragma unroll 4
    for (int e = start; e < end; ++e) {
        const int si = csr[e];
        const float al = alphaE[(size_t)e * 4 + head];
        const ushort4 hv = *(const ushort4*)&hg1[(size_t)si * 256 + c];
        acc0 = fmaf(al, bf2f(hv.x), acc0);
        acc1 = fmaf(al, bf2f(hv.y), acc1);
        acc2 = fmaf(al, bf2f(hv.z), acc2);
        acc3 = fmaf(al, bf2f(hv.w), acc3);
    }
    const float4 bv = *(const float4*)&bias[c];
    float4 o = {acc0 + bv.x, acc1 + bv.y, acc2 + bv.z, acc3 + bv.w};
    *(float4*)&out1[(size_t)d * 256 + c] = o;
}

// ---------------- GraphNorm ----------------
__global__ __launch_bounds__(256) void k_colstat(const float* __restrict__ out1,
    float* __restrict__ colsum, float* __restrict__ colsq, int n)
{
    const int t = threadIdx.x;
    float s = 0.f, q = 0.f;
    for (int r = blockIdx.x; r < n; r += gridDim.x) {
        float v = out1[(size_t)r * 256 + t];
        s += v;
        q += v * v;
    }
    atomicAdd(&colsum[t], s);
    atomicAdd(&colsq[t], q);
}

__global__ void k_norm_params(const float* __restrict__ colsum, const float* __restrict__ colsq,
    const float* __restrict__ gw, const float* __restrict__ gb, const float* __restrict__ gms,
    float* __restrict__ scale, float* __restrict__ shift, int n)
{
    const int t = threadIdx.x;
    const float invn = 1.f / (float)n;
    const float mean = colsum[t] * invn;
    const float msq = colsq[t] * invn;
    const float ms = gms[t];
    const float var = msq - 2.f * ms * mean * mean + ms * ms * mean * mean;
    const float sc = gw[t] * rsqrtf(var + GEPS);
    scale[t] = sc;
    shift[t] = gb[t] - mean * ms * sc;
}

// ---------------- GAT2 alpha precompute ----------------
__global__ __launch_bounds__(256) void k_alpha2(
    const float* __restrict__ a2s, const float* __restrict__ a2d,
    const int* __restrict__ offs, const int* __restrict__ csr,
    float* __restrict__ alphaE2, int n)
{
    const int l = threadIdx.x & 15;
    const int d = blockIdx.x * 16 + (threadIdx.x >> 4);
    if (d >= n) return;
    const int start = offs[d], end = offs[d + 1];
    const float adv = a2d[d];
    float m = -1e30f, s = 0.f;
    for (int e = start + l; e < end; e += 16) {
        const float lv = lrelu(a2s[csr[e]] + adv);
        const float nm = fmaxf(m, lv);
        s = s * __expf(m - nm) + __expf(lv - nm);
        m = nm;
    }
    for (int off = 1; off < 16; off <<= 1) {
        const float om = __shfl_xor(m, off, 16), os = __shfl_xor(s, off, 16);
        const float nm = fmaxf(m, om);
        s = s * __expf(m - nm) + os * __expf(om - nm);
        m = nm;
    }
    const float inv = 1.f / (s + 1e-16f);
    for (int e = start + l; e < end; e += 16)
        alphaE2[e] = __expf(lrelu(a2s[csr[e]] + adv) - m) * inv;
}

// ---------------- GAT2 PV + bias + log_softmax: 32-lane group per node ----------------
__global__ __launch_bounds__(256) void k_pv2(
    const ushortT* __restrict__ hg2, const float* __restrict__ alphaE2,
    const int* __restrict__ offs, const int* __restrict__ csr,
    const float* __restrict__ bias, float* __restrict__ out, int n)
{
    const int l = threadIdx.x & 31;
    const int d = blockIdx.x * 8 + (threadIdx.x >> 5);
    if (d >= n) return;
    const int start = offs[d], end = offs[d + 1];
    float acc = 0.f;
    #pragma unroll 4
    for (int e = start; e < end; ++e) {
        const int si = csr[e];
        const float al = alphaE2[e];
        acc = fmaf(al, bf2f(hg2[(size_t)si * 32 + l]), acc);
    }
    const float v = acc + bias[l];
    float mx = v;
    for (int off = 16; off; off >>= 1) mx = fmaxf(mx, __shfl_xor(mx, off, 32));
    float se = __expf(v - mx);
    for (int off = 16; off; off >>= 1) se += __shfl_xor(se, off, 32);
    out[(size_t)d * 32 + l] = v - mx - __logf(se);
}

// ---------------- launcher ----------------
extern "C" void kernel_launch(void* const* d_in, const int* in_sizes, int n_in,
                              void* d_out, int out_size, void* d_ws, size_t ws_size,
                              hipStream_t stream)
{
    const float* x    = (const float*)d_in[0];
    const int*   ei   = (const int*)d_in[1];
    const float* t1w  = (const float*)d_in[2];
    const float* t1b  = (const float*)d_in[3];
    const float* t2w  = (const float*)d_in[4];
    const float* t2b  = (const float*)d_in[5];
    const float* g1w  = (const float*)d_in[6];
    const float* g1as = (const float*)d_in[7];
    const float* g1ad = (const float*)d_in[8];
    const float* g1b  = (const float*)d_in[9];
    const float* gnw  = (const float*)d_in[10];
    const float* gnb  = (const float*)d_in[11];
    const float* gnms = (const float*)d_in[12];
    const float* g2w  = (const float*)d_in[13];
    const float* g2as = (const float*)d_in[14];
    const float* g2ad = (const float*)d_in[15];
    const float* g2b  = (const float*)d_in[16];

    const int N = in_sizes[0] / 256;
    const int E = in_sizes[1] / 2;
    const int* srcA = ei;
    const int* dstA = ei + E;

    char* ws = (char*)d_ws;
    size_t cur = 0;
    auto alloc = [&](size_t bytes) -> char* {
        char* p = ws + cur;
        cur += (bytes + 255) & ~(size_t)255;
        return p;
    };
    ushortT* h1      = (ushortT*)alloc((size_t)N * 128 * 2);
    ushortT* h2      = (ushortT*)alloc((size_t)N * 64 * 2);
    ushortT* hg1     = (ushortT*)alloc((size_t)N * 256 * 2);
    float*   a1s     = (float*)alloc((size_t)N * 4 * 4);
    float*   a1d     = (float*)alloc((size_t)N * 4 * 4);
    float*   out1    = (float*)alloc((size_t)N * 256 * 4);
    ushortT* hg2     = (ushortT*)alloc((size_t)N * 32 * 2);
    float*   a2s     = (float*)alloc((size_t)N * 4);
    float*   a2d     = (float*)alloc((size_t)N * 4);
    int*     deg     = (int*)alloc((size_t)(N + 1) * 4);
    int*     offs    = (int*)alloc((size_t)(N + 1) * 4);
    int*     cursor  = (int*)alloc((size_t)N * 4);
    int*     bsum    = (int*)alloc(1024);
    int*     csr     = (int*)alloc((size_t)E * 4);
    float*   alphaE  = (float*)alloc((size_t)E * 4 * 4);
    float*   alphaE2 = (float*)alloc((size_t)E * 4);
    float*   colsum  = (float*)alloc(1024);
    float*   colsq   = (float*)alloc(1024);
    float*   cscale  = (float*)alloc(1024);
    float*   cshift  = (float*)alloc(1024);
    ushortT* w1t     = (ushortT*)alloc(128 * 256 * 2);
    ushortT* w2t     = (ushortT*)alloc(64 * 128 * 2);
    ushortT* g1t     = (ushortT*)alloc(256 * 64 * 2);
    ushortT* g2t     = (ushortT*)alloc(32 * 256 * 2);

    hipMemsetAsync(deg, 0, (size_t)(N + 1) * 4, stream);
    hipMemsetAsync(colsum, 0, 2048, stream);

    const int EB  = (E + 255) / 256;
    const int NB  = (N + 255) / 256;
    const int B64 = (N + 63) / 64;
    const int B16 = (N + 15) / 16;
    const int B8  = (N + 7) / 8;
    const int B4  = (N + 3) / 4;

    k_prep<<<128, 256, 0, stream>>>(t1w, t2w, g1w, g2w, w1t, w2t, g1t, g2t);
    k_lin1<<<B64, 256, 0, stream>>>(x, w1t, t1b, h1, N);
    k_lin2<<<B64, 256, 0, stream>>>(h1, w2t, t2b, h2, N);
    k_g1feat<<<B64, 256, 0, stream>>>(h2, g1t, g1as, g1ad, hg1, a1s, a1d, N);
    k_hist<<<EB, 256, 0, stream>>>(dstA, deg, E);
    k_scan1<<<NB, 256, 0, stream>>>(deg, offs, bsum, N);
    k_scan2<<<1, 256, 0, stream>>>(bsum, NB);
    k_scan3<<<NB, 256, 0, stream>>>(offs, cursor, bsum, N, E);
    k_scatter<<<EB, 256, 0, stream>>>(srcA, dstA, cursor, csr, E);
    k_alpha1<<<B16, 256, 0, stream>>>(a1s, a1d, offs, csr, alphaE, N);
    k_pv1<<<B4, 256, 0, stream>>>(hg1, alphaE, offs, csr, g1b, out1, N);
    k_colstat<<<256, 256, 0, stream>>>(out1, colsum, colsq, N);
    k_norm_params<<<1, 256, 0, stream>>>(colsum, colsq, gnw, gnb, gnms, cscale, cshift, N);
    k_g2feat<<<B64, 256, 0, stream>>>(out1, cscale, cshift, g2t, g2as, g2ad, hg2, a2s, a2d, N);
    k_alpha2<<<B16, 256, 0, stream>>>(a2s, a2d, offs, csr, alphaE2, N);
    k_pv2<<<B8, 256, 0, stream>>>(hg2, alphaE2, offs, csr, g2b, (float*)d_out, N);
}

// Round 6
// 319.864 us; speedup vs baseline: 2.4067x; 1.0152x over previous
//
#include <hip/hip_runtime.h>

#define NSLOPE 0.2f
#define GEPS 1e-5f

typedef unsigned short ushortT;
typedef __attribute__((ext_vector_type(8))) unsigned short us8;
typedef __attribute__((ext_vector_type(8))) __bf16 bf16x8;
typedef __attribute__((ext_vector_type(4))) float f32x4;

__device__ __forceinline__ float lrelu(float x) { return x >= 0.f ? x : NSLOPE * x; }
__device__ __forceinline__ ushortT f2bf(float f) {
    unsigned int u = __float_as_uint(f);
    return (ushortT)((u + 0x7fffu + ((u >> 16) & 1u)) >> 16);
}
__device__ __forceinline__ float bf2f(ushortT h) {
    return __uint_as_float((unsigned int)h << 16);
}

// ---------------- weight prep: transpose + bf16 convert ----------------
__global__ __launch_bounds__(256) void k_prep(
    const float* __restrict__ w1, const float* __restrict__ w2,
    const float* __restrict__ g1w, const float* __restrict__ g2w,
    ushortT* __restrict__ w1t, ushortT* __restrict__ w2t,
    ushortT* __restrict__ g1t, ushortT* __restrict__ g2t)
{
    const int i = blockIdx.x * 256 + threadIdx.x;
    if (i < 128 * 256) { const int c = i >> 8, k = i & 255; w1t[i] = f2bf(w1[k * 128 + c]); }
    if (i < 64 * 128)  { const int c = i >> 7, k = i & 127; w2t[i] = f2bf(w2[k * 64 + c]); }
    if (i < 256 * 64)  { const int c = i >> 6, k = i & 63;  g1t[i] = f2bf(g1w[k * 256 + c]); }
    if (i < 32 * 256)  { const int c = i >> 8, k = i & 255; g2t[i] = f2bf(g2w[k * 32 + c]); }
}

// ---------------- MFMA GEMM 1: h1(bf16) = relu(x @ w1 + b1)  [N,256]x[256,128] ----------------
__global__ __launch_bounds__(256) void k_lin1(const float* __restrict__ x,
    const ushortT* __restrict__ w1t, const float* __restrict__ b1,
    ushortT* __restrict__ h1, int n)
{
    __shared__ us8 Ab[64 * 128 / 16];    // 64 rows x 64 bf16, swizzled
    __shared__ us8 Bb[128 * 128 / 16];   // 128 cols x 64 bf16
    char* A = (char*)Ab; char* B = (char*)Bb;
    const int t = threadIdx.x;
    const int w = t >> 6, l = t & 63;
    const int lo = l & 15, hi = l >> 4;
    const int n0 = blockIdx.x * 64;
    const int wm = (w >> 1) * 32, wn = (w & 1) * 64;
    f32x4 acc[2][4];
    #pragma unroll
    for (int mf = 0; mf < 2; ++mf)
        #pragma unroll
        for (int nf = 0; nf < 4; ++nf) acc[mf][nf] = (f32x4){0.f, 0.f, 0.f, 0.f};

    const int arow = t >> 2, ak0 = (t & 3) * 16;
    int agn = n0 + arow; if (agn >= n) agn = n - 1;
    const int asw = (arow & 7) << 4;

    for (int kc = 0; kc < 4; ++kc) {
        __syncthreads();
        {   // stage A (fp32 -> bf16)
            ushortT tmp[16];
            const float* xp = &x[(size_t)agn * 256 + kc * 64 + ak0];
            #pragma unroll
            for (int j = 0; j < 4; ++j) {
                const float4 v = *(const float4*)(xp + j * 4);
                tmp[j*4+0] = f2bf(v.x); tmp[j*4+1] = f2bf(v.y);
                tmp[j*4+2] = f2bf(v.z); tmp[j*4+3] = f2bf(v.w);
            }
            *(us8*)(A + arow * 128 + ((ak0 * 2) ^ asw)) = *(us8*)tmp;
            *(us8*)(A + arow * 128 + ((ak0 * 2 + 16) ^ asw)) = *(us8*)(tmp + 8);
        }
        #pragma unroll
        for (int i = 0; i < 4; ++i) {   // stage B
            const int idx = i * 256 + t, br = idx >> 3, bs = idx & 7;
            const us8 v = *(const us8*)&w1t[(size_t)br * 256 + kc * 64 + bs * 8];
            *(us8*)(B + br * 128 + ((bs * 16) ^ ((br & 7) << 4))) = v;
        }
        __syncthreads();
        #pragma unroll
        for (int ks = 0; ks < 2; ++ks) {
            const int koff = ks * 64 + hi * 16;
            bf16x8 af[2], bf[4];
            #pragma unroll
            for (int mf = 0; mf < 2; ++mf) {
                const int r = wm + mf * 16 + lo;
                af[mf] = *(const bf16x8*)(A + r * 128 + (koff ^ ((r & 7) << 4)));
            }
            #pragma unroll
            for (int nf = 0; nf < 4; ++nf) {
                const int r = wn + nf * 16 + lo;
                bf[nf] = *(const bf16x8*)(B + r * 128 + (koff ^ ((r & 7) << 4)));
            }
            #pragma unroll
            for (int mf = 0; mf < 2; ++mf)
                #pragma unroll
                for (int nf = 0; nf < 4; ++nf)
                    acc[mf][nf] = __builtin_amdgcn_mfma_f32_16x16x32_bf16(af[mf], bf[nf], acc[mf][nf], 0, 0, 0);
        }
    }
    #pragma unroll
    for (int nf = 0; nf < 4; ++nf) {
        const int col = wn + nf * 16 + lo;
        const float bb = b1[col];
        #pragma unroll
        for (int mf = 0; mf < 2; ++mf)
            #pragma unroll
            for (int j = 0; j < 4; ++j) {
                const int r = n0 + wm + mf * 16 + hi * 4 + j;
                if (r < n) h1[(size_t)r * 128 + col] = f2bf(fmaxf(acc[mf][nf][j] + bb, 0.f));
            }
    }
}

// ---------------- MFMA GEMM 2: h2(bf16) = relu(h1 @ w2 + b2)  [N,128]x[128,64] ----------------
__global__ __launch_bounds__(256) void k_lin2(const ushortT* __restrict__ h1,
    const ushortT* __restrict__ w2t, const float* __restrict__ b2,
    ushortT* __restrict__ h2, int n)
{
    __shared__ us8 Ab[64 * 128 / 16];
    __shared__ us8 Bb[64 * 128 / 16];
    char* A = (char*)Ab; char* B = (char*)Bb;
    const int t = threadIdx.x;
    const int w = t >> 6, l = t & 63;
    const int lo = l & 15, hi = l >> 4;
    const int n0 = blockIdx.x * 64;
    const int wm = (w >> 1) * 32, wn = (w & 1) * 32;
    f32x4 acc[2][2];
    #pragma unroll
    for (int mf = 0; mf < 2; ++mf)
        #pragma unroll
        for (int nf = 0; nf < 2; ++nf) acc[mf][nf] = (f32x4){0.f, 0.f, 0.f, 0.f};

    const int arow = t >> 2, ak0 = (t & 3) * 16;
    int agn = n0 + arow; if (agn >= n) agn = n - 1;
    const int asw = (arow & 7) << 4;

    for (int kc = 0; kc < 2; ++kc) {
        __syncthreads();
        {
            const us8 v0 = *(const us8*)&h1[(size_t)agn * 128 + kc * 64 + ak0];
            const us8 v1 = *(const us8*)&h1[(size_t)agn * 128 + kc * 64 + ak0 + 8];
            *(us8*)(A + arow * 128 + ((ak0 * 2) ^ asw)) = v0;
            *(us8*)(A + arow * 128 + ((ak0 * 2 + 16) ^ asw)) = v1;
        }
        #pragma unroll
        for (int i = 0; i < 2; ++i) {
            const int idx = i * 256 + t, br = idx >> 3, bs = idx & 7;
            const us8 v = *(const us8*)&w2t[(size_t)br * 128 + kc * 64 + bs * 8];
            *(us8*)(B + br * 128 + ((bs * 16) ^ ((br & 7) << 4))) = v;
        }
        __syncthreads();
        #pragma unroll
        for (int ks = 0; ks < 2; ++ks) {
            const int koff = ks * 64 + hi * 16;
            bf16x8 af[2], bf[2];
            #pragma unroll
            for (int mf = 0; mf < 2; ++mf) {
                const int r = wm + mf * 16 + lo;
                af[mf] = *(const bf16x8*)(A + r * 128 + (koff ^ ((r & 7) << 4)));
            }
            #pragma unroll
            for (int nf = 0; nf < 2; ++nf) {
                const int r = wn + nf * 16 + lo;
                bf[nf] = *(const bf16x8*)(B + r * 128 + (koff ^ ((r & 7) << 4)));
            }
            #pragma unroll
            for (int mf = 0; mf < 2; ++mf)
                #pragma unroll
                for (int nf = 0; nf < 2; ++nf)
                    acc[mf][nf] = __builtin_amdgcn_mfma_f32_16x16x32_bf16(af[mf], bf[nf], acc[mf][nf], 0, 0, 0);
        }
    }
    #pragma unroll
    for (int nf = 0; nf < 2; ++nf) {
        const int col = wn + nf * 16 + lo;
        const float bb = b2[col];
        #pragma unroll
        for (int mf = 0; mf < 2; ++mf)
            #pragma unroll
            for (int j = 0; j < 4; ++j) {
                const int r = n0 + wm + mf * 16 + hi * 4 + j;
                if (r < n) h2[(size_t)r * 64 + col] = f2bf(fmaxf(acc[mf][nf][j] + bb, 0.f));
            }
    }
}

// ---------------- MFMA GEMM 3: hg1(bf16) = h2 @ g1w ; a1s/a1d  [N,64]x[64,256] ----------------
__global__ __launch_bounds__(256) void k_g1feat(const ushortT* __restrict__ h2,
    const ushortT* __restrict__ g1t, const float* __restrict__ attS, const float* __restrict__ attD,
    ushortT* __restrict__ hg1, float* __restrict__ a1s, float* __restrict__ a1d, int n)
{
    __shared__ us8 Ab[64 * 128 / 16];
    __shared__ us8 Bb[256 * 128 / 16];
    char* A = (char*)Ab; char* B = (char*)Bb;
    const int t = threadIdx.x;
    const int w = t >> 6, l = t & 63;
    const int lo = l & 15, hi = l >> 4;
    const int n0 = blockIdx.x * 64;
    const int wm = (w >> 1) * 32, wn = (w & 1) * 128;
    f32x4 acc[2][8];
    #pragma unroll
    for (int mf = 0; mf < 2; ++mf)
        #pragma unroll
        for (int nf = 0; nf < 8; ++nf) acc[mf][nf] = (f32x4){0.f, 0.f, 0.f, 0.f};

    {   // stage A (h2 bf16, K=64 full)
        const int arow = t >> 2, ak0 = (t & 3) * 16;
        int agn = n0 + arow; if (agn >= n) agn = n - 1;
        const int asw = (arow & 7) << 4;
        const us8 v0 = *(const us8*)&h2[(size_t)agn * 64 + ak0];
        const us8 v1 = *(const us8*)&h2[(size_t)agn * 64 + ak0 + 8];
        *(us8*)(A + arow * 128 + ((ak0 * 2) ^ asw)) = v0;
        *(us8*)(A + arow * 128 + ((ak0 * 2 + 16) ^ asw)) = v1;
    }
    #pragma unroll
    for (int i = 0; i < 8; ++i) {
        const int idx = i * 256 + t, br = idx >> 3, bs = idx & 7;
        const us8 v = *(const us8*)&g1t[(size_t)br * 64 + bs * 8];
        *(us8*)(B + br * 128 + ((bs * 16) ^ ((br & 7) << 4))) = v;
    }
    __syncthreads();
    #pragma unroll
    for (int ks = 0; ks < 2; ++ks) {
        const int koff = ks * 64 + hi * 16;
        bf16x8 af[2];
        #pragma unroll
        for (int mf = 0; mf < 2; ++mf) {
            const int r = wm + mf * 16 + lo;
            af[mf] = *(const bf16x8*)(A + r * 128 + (koff ^ ((r & 7) << 4)));
        }
        #pragma unroll
        for (int nf = 0; nf < 8; ++nf) {
            const int r = wn + nf * 16 + lo;
            const bf16x8 bf = *(const bf16x8*)(B + r * 128 + (koff ^ ((r & 7) << 4)));
            #pragma unroll
            for (int mf = 0; mf < 2; ++mf)
                acc[mf][nf] = __builtin_amdgcn_mfma_f32_16x16x32_bf16(af[mf], bf, acc[mf][nf], 0, 0, 0);
        }
    }
    // epilogue: bf16 store + att dot-products
    float sS[8], sD[8];
    #pragma unroll
    for (int nf = 0; nf < 8; ++nf) {
        sS[nf] = attS[wn + nf * 16 + lo];
        sD[nf] = attD[wn + nf * 16 + lo];
    }
    const int hA = wn >> 6, hB = hA + 1;
    #pragma unroll
    for (int mf = 0; mf < 2; ++mf)
        #pragma unroll
        for (int j = 0; j < 4; ++j) {
            const int r = n0 + wm + mf * 16 + hi * 4 + j;
            float pSA = 0.f, pDA = 0.f, pSB = 0.f, pDB = 0.f;
            #pragma unroll
            for (int nf = 0; nf < 4; ++nf) {
                pSA = fmaf(acc[mf][nf][j], sS[nf], pSA);
                pDA = fmaf(acc[mf][nf][j], sD[nf], pDA);
                pSB = fmaf(acc[mf][nf + 4][j], sS[nf + 4], pSB);
                pDB = fmaf(acc[mf][nf + 4][j], sD[nf + 4], pDB);
            }
            #pragma unroll
            for (int off = 1; off < 16; off <<= 1) {
                pSA += __shfl_xor(pSA, off);
                pDA += __shfl_xor(pDA, off);
                pSB += __shfl_xor(pSB, off);
                pDB += __shfl_xor(pDB, off);
            }
            if (r < n) {
                if (lo == 0) {
                    a1s[r * 4 + hA] = pSA; a1s[r * 4 + hB] = pSB;
                    a1d[r * 4 + hA] = pDA; a1d[r * 4 + hB] = pDB;
                }
                #pragma unroll
                for (int nf = 0; nf < 8; ++nf)
                    hg1[(size_t)r * 256 + wn + nf * 16 + lo] = f2bf(acc[mf][nf][j]);
            }
        }
}

// ---------------- MFMA GEMM 4: hg2(bf16) = elu(norm(out1)) @ g2w ; a2s/a2d  [N,256]x[256,32] ----------------
__global__ __launch_bounds__(256) void k_g2feat(const ushortT* __restrict__ out1,
    const float* __restrict__ cscale, const float* __restrict__ cshift,
    const ushortT* __restrict__ g2t, const float* __restrict__ attS, const float* __restrict__ attD,
    ushortT* __restrict__ hg2, float* __restrict__ a2s, float* __restrict__ a2d, int n)
{
    __shared__ us8 Ab[64 * 128 / 16];
    __shared__ us8 Bb[32 * 128 / 16];
    char* A = (char*)Ab; char* B = (char*)Bb;
    const int t = threadIdx.x;
    const int w = t >> 6, l = t & 63;
    const int lo = l & 15, hi = l >> 4;
    const int n0 = blockIdx.x * 64;
    const int wm = w * 16;
    f32x4 acc[2];
    acc[0] = (f32x4){0.f, 0.f, 0.f, 0.f};
    acc[1] = (f32x4){0.f, 0.f, 0.f, 0.f};

    const int arow = t >> 2, ak0 = (t & 3) * 16;
    int agn = n0 + arow; if (agn >= n) agn = n - 1;
    const int asw = (arow & 7) << 4;

    for (int kc = 0; kc < 4; ++kc) {
        __syncthreads();
        {   // stage A with norm + elu (bf16 source)
            ushortT tmp[16];
            const us8 v0 = *(const us8*)&out1[(size_t)agn * 256 + kc * 64 + ak0];
            const us8 v1 = *(const us8*)&out1[(size_t)agn * 256 + kc * 64 + ak0 + 8];
            #pragma unroll
            for (int j = 0; j < 8; ++j) {
                float a = bf2f(v0[j]) * cscale[kc * 64 + ak0 + j] + cshift[kc * 64 + ak0 + j];
                float b = bf2f(v1[j]) * cscale[kc * 64 + ak0 + 8 + j] + cshift[kc * 64 + ak0 + 8 + j];
                a = a > 0.f ? a : __expf(a) - 1.f;
                b = b > 0.f ? b : __expf(b) - 1.f;
                tmp[j] = f2bf(a); tmp[8 + j] = f2bf(b);
            }
            *(us8*)(A + arow * 128 + ((ak0 * 2) ^ asw)) = *(us8*)tmp;
            *(us8*)(A + arow * 128 + ((ak0 * 2 + 16) ^ asw)) = *(us8*)(tmp + 8);
        }
        {   // stage B: 32 rows x 8 segs = 256
            const int br = t >> 3, bs = t & 7;
            const us8 v = *(const us8*)&g2t[(size_t)br * 256 + kc * 64 + bs * 8];
            *(us8*)(B + br * 128 + ((bs * 16) ^ ((br & 7) << 4))) = v;
        }
        __syncthreads();
        #pragma unroll
        for (int ks = 0; ks < 2; ++ks) {
            const int koff = ks * 64 + hi * 16;
            const int ra = wm + lo;
            const bf16x8 af = *(const bf16x8*)(A + ra * 128 + (koff ^ ((ra & 7) << 4)));
            #pragma unroll
            for (int nf = 0; nf < 2; ++nf) {
                const int r = nf * 16 + lo;
                const bf16x8 bf = *(const bf16x8*)(B + r * 128 + (koff ^ ((r & 7) << 4)));
                acc[nf] = __builtin_amdgcn_mfma_f32_16x16x32_bf16(af, bf, acc[nf], 0, 0, 0);
            }
        }
    }
    float sS[2], sD[2];
    sS[0] = attS[lo]; sS[1] = attS[16 + lo];
    sD[0] = attD[lo]; sD[1] = attD[16 + lo];
    #pragma unroll
    for (int j = 0; j < 4; ++j) {
        const int r = n0 + wm + hi * 4 + j;
        float pS = fmaf(acc[0][j], sS[0], acc[1][j] * sS[1]);
        float pD = fmaf(acc[0][j], sD[0], acc[1][j] * sD[1]);
        #pragma unroll
        for (int off = 1; off < 16; off <<= 1) {
            pS += __shfl_xor(pS, off);
            pD += __shfl_xor(pD, off);
        }
        if (r < n) {
            if (lo == 0) { a2s[r] = pS; a2d[r] = pD; }
            hg2[(size_t)r * 32 + lo] = f2bf(acc[0][j]);
            hg2[(size_t)r * 32 + 16 + lo] = f2bf(acc[1][j]);
        }
    }
}

// ---------------- CSR build ----------------
__global__ void k_hist(const int* __restrict__ dst, int* __restrict__ deg, int e) {
    int i = blockIdx.x * 256 + threadIdx.x;
    if (i < e) atomicAdd(&deg[dst[i]], 1);
}

__global__ __launch_bounds__(256) void k_scan1(const int* __restrict__ deg, int* __restrict__ offs,
                                               int* __restrict__ bsum, int n)
{
    __shared__ int sm[256];
    const int t = threadIdx.x;
    const int i = blockIdx.x * 256 + t;
    const int v = (i < n) ? deg[i] : 0;
    sm[t] = v;
    __syncthreads();
    for (int off = 1; off < 256; off <<= 1) {
        int add = (t >= off) ? sm[t - off] : 0;
        __syncthreads();
        sm[t] += add;
        __syncthreads();
    }
    if (i < n) offs[i] = sm[t] - v;
    if (t == 255) bsum[blockIdx.x] = sm[255];
}

__global__ __launch_bounds__(256) void k_scan2(int* __restrict__ bsum, int nb) {
    __shared__ int sm[256];
    const int t = threadIdx.x;
    const int v = (t < nb) ? bsum[t] : 0;
    sm[t] = v;
    __syncthreads();
    for (int off = 1; off < 256; off <<= 1) {
        int add = (t >= off) ? sm[t - off] : 0;
        __syncthreads();
        sm[t] += add;
        __syncthreads();
    }
    if (t < nb) bsum[t] = sm[t] - v;
}

__global__ void k_scan3(int* __restrict__ offs, int* __restrict__ cursor,
                        const int* __restrict__ bsum, int n, int e) {
    int i = blockIdx.x * 256 + threadIdx.x;
    if (i < n) {
        int o = offs[i] + bsum[i >> 8];
        offs[i] = o;
        cursor[i] = o;
    }
    if (i == 0) offs[n] = e;
}

__global__ void k_scatter(const int* __restrict__ src, const int* __restrict__ dst,
                          int* __restrict__ cursor, int* __restrict__ csr, int e) {
    int i = blockIdx.x * 256 + threadIdx.x;
    if (i < e) {
        int p = atomicAdd(&cursor[dst[i]], 1);
        csr[p] = src[i];
    }
}

// ---------------- GAT1 alpha precompute: 16-lane group per node ----------------
__global__ __launch_bounds__(256) void k_alpha1(
    const float* __restrict__ a1s, const float* __restrict__ a1d,
    const int* __restrict__ offs, const int* __restrict__ csr,
    float* __restrict__ alphaE, int n)
{
    const int l = threadIdx.x & 15;
    const int d = blockIdx.x * 16 + (threadIdx.x >> 4);
    if (d >= n) return;
    const int start = offs[d], end = offs[d + 1];
    const float4* __restrict__ a1s4 = (const float4*)a1s;
    const float4 adv = ((const float4*)a1d)[d];
    const float ad0 = adv.x, ad1 = adv.y, ad2 = adv.z, ad3 = adv.w;

    float m0 = -1e30f, m1 = -1e30f, m2 = -1e30f, m3 = -1e30f;
    float s0 = 0.f, s1 = 0.f, s2 = 0.f, s3 = 0.f;
    for (int e = start + l; e < end; e += 16) {
        const float4 av = a1s4[csr[e]];
        const float l0 = lrelu(av.x + ad0), l1 = lrelu(av.y + ad1);
        const float l2 = lrelu(av.z + ad2), l3 = lrelu(av.w + ad3);
        float nm;
        nm = fmaxf(m0, l0); s0 = s0 * __expf(m0 - nm) + __expf(l0 - nm); m0 = nm;
        nm = fmaxf(m1, l1); s1 = s1 * __expf(m1 - nm) + __expf(l1 - nm); m1 = nm;
        nm = fmaxf(m2, l2); s2 = s2 * __expf(m2 - nm) + __expf(l2 - nm); m2 = nm;
        nm = fmaxf(m3, l3); s3 = s3 * __expf(m3 - nm) + __expf(l3 - nm); m3 = nm;
    }
    for (int off = 1; off < 16; off <<= 1) {
        float om, os, nm;
        om = __shfl_xor(m0, off, 16); os = __shfl_xor(s0, off, 16);
        nm = fmaxf(m0, om); s0 = s0 * __expf(m0 - nm) + os * __expf(om - nm); m0 = nm;
        om = __shfl_xor(m1, off, 16); os = __shfl_xor(s1, off, 16);
        nm = fmaxf(m1, om); s1 = s1 * __expf(m1 - nm) + os * __expf(om - nm); m1 = nm;
        om = __shfl_xor(m2, off, 16); os = __shfl_xor(s2, off, 16);
        nm = fmaxf(m2, om); s2 = s2 * __expf(m2 - nm) + os * __expf(om - nm); m2 = nm;
        om = __shfl_xor(m3, off, 16); os = __shfl_xor(s3, off, 16);
        nm = fmaxf(m3, om); s3 = s3 * __expf(m3 - nm) + os * __expf(om - nm); m3 = nm;
    }
    const float i0 = 1.f / (s0 + 1e-16f), i1 = 1.f / (s1 + 1e-16f);
    const float i2 = 1.f / (s2 + 1e-16f), i3 = 1.f / (s3 + 1e-16f);
    for (int e = start + l; e < end; e += 16) {
        const float4 av = a1s4[csr[e]];
        float4 o;
        o.x = __expf(lrelu(av.x + ad0) - m0) * i0;
        o.y = __expf(lrelu(av.y + ad1) - m1) * i1;
        o.z = __expf(lrelu(av.z + ad2) - m2) * i2;
        o.w = __expf(lrelu(av.w + ad3) - m3) * i3;
        *(float4*)&alphaE[(size_t)e * 4] = o;
    }
}

// ---------------- GAT1 PV gather: wave per node, LDS-staged metadata ----------------
__global__ __launch_bounds__(256) void k_pv1(
    const ushortT* __restrict__ hg1, const float* __restrict__ alphaE,
    const int* __restrict__ offs, const int* __restrict__ csr,
    const float* __restrict__ bias, ushortT* __restrict__ out1, int n)
{
    __shared__ int sSid[4][64];
    __shared__ float sAl[4][256];
    const int lane = threadIdx.x & 63, w = threadIdx.x >> 6;
    const int d = blockIdx.x * 4 + w;
    if (d >= n) return;
    const int start = offs[d], end = offs[d + 1];
    const int c = lane * 4;
    const int head = lane >> 4;
    float acc0 = 0.f, acc1 = 0.f, acc2 = 0.f, acc3 = 0.f;
    for (int base = start; base < end; base += 64) {
        const int cnt = min(64, end - base);
        if (lane < cnt) {
            sSid[w][lane] = csr[base + lane];
            *(float4*)&sAl[w][lane * 4] = *(const float4*)&alphaE[(size_t)(base + lane) * 4];
        }
        // same-wave LDS produce->consume: program order + compiler lgkmcnt
        #pragma unroll 8
        for (int i = 0; i < cnt; ++i) {
            const int si = sSid[w][i];
            const float al = sAl[w][i * 4 + head];
            const ushort4 hv = *(const ushort4*)&hg1[(size_t)si * 256 + c];
            acc0 = fmaf(al, bf2f(hv.x), acc0);
            acc1 = fmaf(al, bf2f(hv.y), acc1);
            acc2 = fmaf(al, bf2f(hv.z), acc2);
            acc3 = fmaf(al, bf2f(hv.w), acc3);
        }
    }
    const float4 bv = *(const float4*)&bias[c];
    ushort4 o;
    o.x = f2bf(acc0 + bv.x); o.y = f2bf(acc1 + bv.y);
    o.z = f2bf(acc2 + bv.z); o.w = f2bf(acc3 + bv.w);
    *(ushort4*)&out1[(size_t)d * 256 + c] = o;
}

// ---------------- GraphNorm (bf16 input) ----------------
__global__ __launch_bounds__(256) void k_colstat(const ushortT* __restrict__ out1,
    float* __restrict__ colsum, float* __restrict__ colsq, int n)
{
    const int t = threadIdx.x;
    float s = 0.f, q = 0.f;
    for (int r = blockIdx.x; r < n; r += gridDim.x) {
        const float v = bf2f(out1[(size_t)r * 256 + t]);
        s += v;
        q += v * v;
    }
    atomicAdd(&colsum[t], s);
    atomicAdd(&colsq[t], q);
}

__global__ void k_norm_params(const float* __restrict__ colsum, const float* __restrict__ colsq,
    const float* __restrict__ gw, const float* __restrict__ gb, const float* __restrict__ gms,
    float* __restrict__ scale, float* __restrict__ shift, int n)
{
    const int t = threadIdx.x;
    const float invn = 1.f / (float)n;
    const float mean = colsum[t] * invn;
    const float msq = colsq[t] * invn;
    const float ms = gms[t];
    const float var = msq - 2.f * ms * mean * mean + ms * ms * mean * mean;
    const float sc = gw[t] * rsqrtf(var + GEPS);
    scale[t] = sc;
    shift[t] = gb[t] - mean * ms * sc;
}

// ---------------- GAT2 alpha precompute ----------------
__global__ __launch_bounds__(256) void k_alpha2(
    const float* __restrict__ a2s, const float* __restrict__ a2d,
    const int* __restrict__ offs, const int* __restrict__ csr,
    float* __restrict__ alphaE2, int n)
{
    const int l = threadIdx.x & 15;
    const int d = blockIdx.x * 16 + (threadIdx.x >> 4);
    if (d >= n) return;
    const int start = offs[d], end = offs[d + 1];
    const float adv = a2d[d];
    float m = -1e30f, s = 0.f;
    for (int e = start + l; e < end; e += 16) {
        const float lv = lrelu(a2s[csr[e]] + adv);
        const float nm = fmaxf(m, lv);
        s = s * __expf(m - nm) + __expf(lv - nm);
        m = nm;
    }
    for (int off = 1; off < 16; off <<= 1) {
        const float om = __shfl_xor(m, off, 16), os = __shfl_xor(s, off, 16);
        const float nm = fmaxf(m, om);
        s = s * __expf(m - nm) + os * __expf(om - nm);
        m = nm;
    }
    const float inv = 1.f / (s + 1e-16f);
    for (int e = start + l; e < end; e += 16)
        alphaE2[e] = __expf(lrelu(a2s[csr[e]] + adv) - m) * inv;
}

// ---------------- GAT2 PV + bias + log_softmax: 32-lane group, LDS-staged metadata ----------------
__global__ __launch_bounds__(256) void k_pv2(
    const ushortT* __restrict__ hg2, const float* __restrict__ alphaE2,
    const int* __restrict__ offs, const int* __restrict__ csr,
    const float* __restrict__ bias, float* __restrict__ out, int n)
{
    __shared__ int sSid[8][32];
    __shared__ float sAl[8][32];
    const int l = threadIdx.x & 31, w = threadIdx.x >> 5;
    const int d = blockIdx.x * 8 + w;
    if (d >= n) return;
    const int start = offs[d], end = offs[d + 1];
    float acc = 0.f;
    for (int base = start; base < end; base += 32) {
        const int cnt = min(32, end - base);
        if (l < cnt) {
            sSid[w][l] = csr[base + l];
            sAl[w][l] = alphaE2[base + l];
        }
        #pragma unroll 8
        for (int i = 0; i < cnt; ++i) {
            const int si = sSid[w][i];
            const float al = sAl[w][i];
            acc = fmaf(al, bf2f(hg2[(size_t)si * 32 + l]), acc);
        }
    }
    const float v = acc + bias[l];
    float mx = v;
    for (int off = 16; off; off >>= 1) mx = fmaxf(mx, __shfl_xor(mx, off, 32));
    float se = __expf(v - mx);
    for (int off = 16; off; off >>= 1) se += __shfl_xor(se, off, 32);
    out[(size_t)d * 32 + l] = v - mx - __logf(se);
}

// ---------------- launcher ----------------
extern "C" void kernel_launch(void* const* d_in, const int* in_sizes, int n_in,
                              void* d_out, int out_size, void* d_ws, size_t ws_size,
                              hipStream_t stream)
{
    const float* x    = (const float*)d_in[0];
    const int*   ei   = (const int*)d_in[1];
    const float* t1w  = (const float*)d_in[2];
    const float* t1b  = (const float*)d_in[3];
    const float* t2w  = (const float*)d_in[4];
    const float* t2b  = (const float*)d_in[5];
    const float* g1w  = (const float*)d_in[6];
    const float* g1as = (const float*)d_in[7];
    const float* g1ad = (const float*)d_in[8];
    const float* g1b  = (const float*)d_in[9];
    const float* gnw  = (const float*)d_in[10];
    const float* gnb  = (const float*)d_in[11];
    const float* gnms = (const float*)d_in[12];
    const float* g2w  = (const float*)d_in[13];
    const float* g2as = (const float*)d_in[14];
    const float* g2ad = (const float*)d_in[15];
    const float* g2b  = (const float*)d_in[16];

    const int N = in_sizes[0] / 256;
    const int E = in_sizes[1] / 2;
    const int* srcA = ei;
    const int* dstA = ei + E;

    char* ws = (char*)d_ws;
    size_t cur = 0;
    auto alloc = [&](size_t bytes) -> char* {
        char* p = ws + cur;
        cur += (bytes + 255) & ~(size_t)255;
        return p;
    };
    ushortT* h1      = (ushortT*)alloc((size_t)N * 128 * 2);
    ushortT* h2      = (ushortT*)alloc((size_t)N * 64 * 2);
    ushortT* hg1     = (ushortT*)alloc((size_t)N * 256 * 2);
    float*   a1s     = (float*)alloc((size_t)N * 4 * 4);
    float*   a1d     = (float*)alloc((size_t)N * 4 * 4);
    ushortT* out1    = (ushortT*)alloc((size_t)N * 256 * 2);
    ushortT* hg2     = (ushortT*)alloc((size_t)N * 32 * 2);
    float*   a2s     = (float*)alloc((size_t)N * 4);
    float*   a2d     = (float*)alloc((size_t)N * 4);
    int*     deg     = (int*)alloc((size_t)(N + 1) * 4);
    int*     offs    = (int*)alloc((size_t)(N + 1) * 4);
    int*     cursor  = (int*)alloc((size_t)N * 4);
    int*     bsum    = (int*)alloc(1024);
    int*     csr     = (int*)alloc((size_t)E * 4);
    float*   alphaE  = (float*)alloc((size_t)E * 4 * 4);
    float*   alphaE2 = (float*)alloc((size_t)E * 4);
    float*   colsum  = (float*)alloc(1024);
    float*   colsq   = (float*)alloc(1024);
    float*   cscale  = (float*)alloc(1024);
    float*   cshift  = (float*)alloc(1024);
    ushortT* w1t     = (ushortT*)alloc(128 * 256 * 2);
    ushortT* w2t     = (ushortT*)alloc(64 * 128 * 2);
    ushortT* g1t     = (ushortT*)alloc(256 * 64 * 2);
    ushortT* g2t     = (ushortT*)alloc(32 * 256 * 2);

    hipMemsetAsync(deg, 0, (size_t)(N + 1) * 4, stream);
    hipMemsetAsync(colsum, 0, 2048, stream);

    const int EB  = (E + 255) / 256;
    const int NB  = (N + 255) / 256;
    const int B64 = (N + 63) / 64;
    const int B16 = (N + 15) / 16;
    const int B8  = (N + 7) / 8;
    const int B4  = (N + 3) / 4;

    k_prep<<<128, 256, 0, stream>>>(t1w, t2w, g1w, g2w, w1t, w2t, g1t, g2t);
    k_lin1<<<B64, 256, 0, stream>>>(x, w1t, t1b, h1, N);
    k_lin2<<<B64, 256, 0, stream>>>(h1, w2t, t2b, h2, N);
    k_g1feat<<<B64, 256, 0, stream>>>(h2, g1t, g1as, g1ad, hg1, a1s, a1d, N);
    k_hist<<<EB, 256, 0, stream>>>(dstA, deg, E);
    k_scan1<<<NB, 256, 0, stream>>>(deg, offs, bsum, N);
    k_scan2<<<1, 256, 0, stream>>>(bsum, NB);
    k_scan3<<<NB, 256, 0, stream>>>(offs, cursor, bsum, N, E);
    k_scatter<<<EB, 256, 0, stream>>>(srcA, dstA, cursor, csr, E);
    k_alpha1<<<B16, 256, 0, stream>>>(a1s, a1d, offs, csr, alphaE, N);
    k_pv1<<<B4, 256, 0, stream>>>(hg1, alphaE, offs, csr, g1b, out1, N);
    k_colstat<<<256, 256, 0, stream>>>(out1, colsum, colsq, N);
    k_norm_params<<<1, 256, 0, stream>>>(colsum, colsq, gnw, gnb, gnms, cscale, cshift, N);
    k_g2feat<<<B64, 256, 0, stream>>>(out1, cscale, cshift, g2t, g2as, g2ad, hg2, a2s, a2d, N);
    k_alpha2<<<B16, 256, 0, stream>>>(a2s, a2d, offs, csr, alphaE2, N);
    k_pv2<<<B8, 256, 0, stream>>>(hg2, alphaE2, offs, csr, g2b, (float*)d_out, N);
}